// Round 6
// baseline (538.304 us; speedup 1.0000x reference)
//
#include <hip/hip_runtime.h>
#include <hip/hip_bf16.h>

#define NN 100000
#define NE 50000
#define NT 2000
#define DD 128
#define NEDGE 1600000
#define HID 512
#define OUTD 128
#define K1 (3*DD)   // 384: X layout [news | ent_agg | top_agg]
#define NBKT 391    // ceil(100000/256) buckets of 256 nodes

typedef __bf16 bf16x8 __attribute__((ext_vector_type(8)));
typedef __bf16 bf16x4 __attribute__((ext_vector_type(4)));
typedef float  f32x4  __attribute__((ext_vector_type(4)));

__device__ __forceinline__ __bf16 f2b(float f) {
    __hip_bfloat16 h = __float2bfloat16(f);
    union { __hip_bfloat16 h; __bf16 b; } u; u.h = h; return u.b;
}

__device__ __forceinline__ void gll16(const void* g, void* l) {
    __builtin_amdgcn_global_load_lds((const __attribute__((address_space(1))) void*)g,
                                     (__attribute__((address_space(3))) void*)l, 16, 0, 0);
}

__device__ __forceinline__ float ftanh(float x) {
    x = fminf(fmaxf(x, -15.f), 15.f);
    float t = __expf(2.f * x);
    return (t - 1.f) / (t + 1.f);
}

// fused counted-vmcnt + barrier (single asm: nothing reorders between; memory-fenced)
__device__ __forceinline__ void sync_v4() { asm volatile("s_waitcnt vmcnt(4)\n\ts_barrier" ::: "memory"); }
__device__ __forceinline__ void sync_v2() { asm volatile("s_waitcnt vmcnt(2)\n\ts_barrier" ::: "memory"); }
__device__ __forceinline__ void sync_lgkm_v2() { asm volatile("s_waitcnt lgkmcnt(0) vmcnt(2)\n\ts_barrier" ::: "memory"); }
__device__ __forceinline__ void sync_lgkm_v0() { asm volatile("s_waitcnt lgkmcnt(0) vmcnt(0)\n\ts_barrier" ::: "memory"); }
__device__ __forceinline__ void bar_only() { asm volatile("s_barrier" ::: "memory"); }

// ---- convert: ent/top tables -> bf16 tables; news -> bf16 into X cols 0..127 ----
__global__ void conv_feats(const float* __restrict__ entf, const float* __restrict__ topf,
                           const float* __restrict__ news,
                           __bf16* __restrict__ entb, __bf16* __restrict__ topb,
                           __bf16* __restrict__ X) {
    long i = ((long)blockIdx.x * 256 + threadIdx.x) * 4;
    const long NEL = (long)NE * DD;            // 6.4M
    const long NTL = (long)NT * DD;            // 0.256M
    if (i < NEL) {
        float4 v = *(const float4*)(entf + i);
        *(bf16x4*)(entb + i) = bf16x4{f2b(v.x), f2b(v.y), f2b(v.z), f2b(v.w)};
    } else if (i < NEL + NTL) {
        long j = i - NEL;
        float4 v = *(const float4*)(topf + j);
        *(bf16x4*)(topb + j) = bf16x4{f2b(v.x), f2b(v.y), f2b(v.z), f2b(v.w)};
    } else {
        long j = i - NEL - NTL;                // 0 .. 12.8M
        long row = j >> 7, col = j & 127;      // news [NN x 128], 4-aligned col
        float4 v = *(const float4*)(news + j);
        *(bf16x4*)(X + row * K1 + col) = bf16x4{f2b(v.x), f2b(v.y), f2b(v.z), f2b(v.w)};
    }
}

// ---- bucket histogram ----
__global__ __launch_bounds__(256) void hist_buckets(const int* __restrict__ er,
                                                    const int* __restrict__ tr,
                                                    int* __restrict__ bc_e,
                                                    int* __restrict__ bc_t) {
    __shared__ int lhe[NBKT], lht[NBKT];
    const int tid = threadIdx.x;
    for (int i = tid; i < NBKT; i += 256) { lhe[i] = 0; lht[i] = 0; }
    __syncthreads();
    const int base = blockIdx.x * 8192;
    #pragma unroll 4
    for (int k = 0; k < 32; k++) {
        int e = base + k * 256 + tid;
        if (e < NEDGE) {
            atomicAdd(&lhe[er[e] >> 8], 1);
            atomicAdd(&lht[tr[e] >> 8], 1);
        }
    }
    __syncthreads();
    for (int i = tid; i < NBKT; i += 256) {
        if (lhe[i]) atomicAdd(&bc_e[i], lhe[i]);
        if (lht[i]) atomicAdd(&bc_t[i], lht[i]);
    }
}

// ---- scan 391 bucket counts ----
__global__ void scan_buckets(int* __restrict__ bc_e, int* __restrict__ bc_t,
                             int* __restrict__ cur_e, int* __restrict__ cur_t,
                             int* __restrict__ offs_e, int* __restrict__ offs_t) {
    int* bc  = blockIdx.y ? bc_t : bc_e;
    int* cur = blockIdx.y ? cur_t : cur_e;
    int* offs = blockIdx.y ? offs_t : offs_e;
    __shared__ int s[512];
    int i = threadIdx.x;
    s[i] = (i < NBKT) ? bc[i] : 0;
    __syncthreads();
    #pragma unroll
    for (int off = 1; off < 512; off <<= 1) {
        int v = (i >= off) ? s[i - off] : 0;
        __syncthreads();
        s[i] += v;
        __syncthreads();
    }
    if (i < NBKT) {
        bc[i] = s[i];
        cur[i] = i ? s[i - 1] : 0;
    }
    if (i == 0) offs[0] = 0;
}

// ---- partition edges into buckets ----
__global__ __launch_bounds__(256) void scatter_bucket(const int* __restrict__ er,
                                                      const int* __restrict__ ec,
                                                      const int* __restrict__ tr,
                                                      const int* __restrict__ tc,
                                                      int* __restrict__ cur_e,
                                                      int* __restrict__ cur_t,
                                                      int* __restrict__ be,
                                                      int* __restrict__ bt) {
    __shared__ int lhe[NBKT], lht[NBKT];
    __shared__ int lbe[NBKT], lbt[NBKT];
    const int tid = threadIdx.x;
    for (int i = tid; i < NBKT; i += 256) { lhe[i] = 0; lht[i] = 0; }
    __syncthreads();
    const int base = blockIdx.x * 4096;
    #pragma unroll 4
    for (int k = 0; k < 16; k++) {
        int e = base + k * 256 + tid;
        if (e < NEDGE) {
            atomicAdd(&lhe[er[e] >> 8], 1);
            atomicAdd(&lht[tr[e] >> 8], 1);
        }
    }
    __syncthreads();
    for (int i = tid; i < NBKT; i += 256) {
        int c = lhe[i];
        lbe[i] = c ? atomicAdd(&cur_e[i], c) : 0;
        lhe[i] = 0;
        c = lht[i];
        lbt[i] = c ? atomicAdd(&cur_t[i], c) : 0;
        lht[i] = 0;
    }
    __syncthreads();
    #pragma unroll 4
    for (int k = 0; k < 16; k++) {
        int e = base + k * 256 + tid;
        if (e < NEDGE) {
            int r = er[e];
            int b = r >> 8;
            int p = lbe[b] + atomicAdd(&lhe[b], 1);
            be[p] = ((r & 255) << 16) | ec[e];
            r = tr[e];
            b = r >> 8;
            p = lbt[b] + atomicAdd(&lht[b], 1);
            bt[p] = ((r & 255) << 16) | tc[e];
        }
    }
}

// ---- per-bucket exact CSR ----
__global__ __launch_bounds__(256) void bucket_csr(const int* __restrict__ be,
                                                  const int* __restrict__ bt,
                                                  const int* __restrict__ bc_e,
                                                  const int* __restrict__ bc_t,
                                                  int* __restrict__ offs_e,
                                                  int* __restrict__ offs_t,
                                                  int* __restrict__ se,
                                                  int* __restrict__ st) {
    const int* buf = blockIdx.y ? bt : be;
    const int* bc  = blockIdx.y ? bc_t : bc_e;
    int* offs      = blockIdx.y ? offs_t : offs_e;
    int* sout      = blockIdx.y ? st : se;
    const int b = blockIdx.x;
    const int tid = threadIdx.x;
    const int start = b ? bc[b - 1] : 0;
    const int cnt = bc[b] - start;

    __shared__ int scn[256];
    __shared__ int lcur[256];
    scn[tid] = 0;
    __syncthreads();
    for (int i = tid; i < cnt; i += 256)
        atomicAdd(&scn[buf[start + i] >> 16], 1);
    __syncthreads();
    #pragma unroll
    for (int off = 1; off < 256; off <<= 1) {
        int v = (tid >= off) ? scn[tid - off] : 0;
        __syncthreads();
        scn[tid] += v;
        __syncthreads();
    }
    const int node = b * 256 + tid;
    if (node < NN) offs[node + 1] = start + scn[tid];
    lcur[tid] = start + (tid ? scn[tid - 1] : 0);
    __syncthreads();
    for (int i = tid; i < cnt; i += 256) {
        int v = buf[start + i];
        int p = atomicAdd(&lcur[v >> 16], 1);
        sout[p] = v & 0xFFFF;
    }
}

// ---- gather-aggregate (bf16 tables) -> X cols 128..383 ----
__global__ __launch_bounds__(256) void aggregate2(const __bf16* __restrict__ entb,
                                                  const __bf16* __restrict__ topb,
                                                  const int* __restrict__ offs_e,
                                                  const int* __restrict__ offs_t,
                                                  const int* __restrict__ se,
                                                  const int* __restrict__ st,
                                                  __bf16* __restrict__ X) {
    const int wave = threadIdx.x >> 6, lane = threadIdx.x & 63;
    const int node = blockIdx.x * 4 + wave;
    if (node >= NN) return;
    const int h = lane >> 4;        // 0..3: edge phase
    const int d = (lane & 15) * 8;  // dim group of 8

    float ea[8] = {0,0,0,0,0,0,0,0};
    float pa[8] = {0,0,0,0,0,0,0,0};

    const int s0 = offs_e[node], s1 = offs_e[node + 1];
    int i = s0 + h;
    for (; i + 12 < s1; i += 16) {
        int c0 = se[i], c1 = se[i + 4], c2 = se[i + 8], c3 = se[i + 12];
        bf16x8 v0 = *(const bf16x8*)(entb + (long)c0 * DD + d);
        bf16x8 v1 = *(const bf16x8*)(entb + (long)c1 * DD + d);
        bf16x8 v2 = *(const bf16x8*)(entb + (long)c2 * DD + d);
        bf16x8 v3 = *(const bf16x8*)(entb + (long)c3 * DD + d);
        #pragma unroll
        for (int j = 0; j < 8; j++)
            ea[j] += ((float)v0[j] + (float)v1[j]) + ((float)v2[j] + (float)v3[j]);
    }
    for (; i < s1; i += 4) {
        bf16x8 v = *(const bf16x8*)(entb + (long)se[i] * DD + d);
        #pragma unroll
        for (int j = 0; j < 8; j++) ea[j] += (float)v[j];
    }

    const int t0 = offs_t[node], t1 = offs_t[node + 1];
    i = t0 + h;
    for (; i + 12 < t1; i += 16) {
        int c0 = st[i], c1 = st[i + 4], c2 = st[i + 8], c3 = st[i + 12];
        bf16x8 v0 = *(const bf16x8*)(topb + (long)c0 * DD + d);
        bf16x8 v1 = *(const bf16x8*)(topb + (long)c1 * DD + d);
        bf16x8 v2 = *(const bf16x8*)(topb + (long)c2 * DD + d);
        bf16x8 v3 = *(const bf16x8*)(topb + (long)c3 * DD + d);
        #pragma unroll
        for (int j = 0; j < 8; j++)
            pa[j] += ((float)v0[j] + (float)v1[j]) + ((float)v2[j] + (float)v3[j]);
    }
    for (; i < t1; i += 4) {
        bf16x8 v = *(const bf16x8*)(topb + (long)st[i] * DD + d);
        #pragma unroll
        for (int j = 0; j < 8; j++) pa[j] += (float)v[j];
    }

    #pragma unroll
    for (int j = 0; j < 8; j++) {
        ea[j] += __shfl_xor(ea[j], 16, 64);
        ea[j] += __shfl_xor(ea[j], 32, 64);
        pa[j] += __shfl_xor(pa[j], 16, 64);
        pa[j] += __shfl_xor(pa[j], 32, 64);
    }

    const float ie = 1.0f / ((float)(s1 - s0) + 1e-8f);
    const float it = 1.0f / ((float)(t1 - t0) + 1e-8f);
    __bf16* xr = X + (long)node * K1;
    if (h == 1) {
        *(bf16x8*)(xr + DD + d) = bf16x8{f2b(ea[0]*ie), f2b(ea[1]*ie), f2b(ea[2]*ie), f2b(ea[3]*ie),
                                         f2b(ea[4]*ie), f2b(ea[5]*ie), f2b(ea[6]*ie), f2b(ea[7]*ie)};
    } else if (h == 2) {
        *(bf16x8*)(xr + 2*DD + d) = bf16x8{f2b(pa[0]*it), f2b(pa[1]*it), f2b(pa[2]*it), f2b(pa[3]*it),
                                           f2b(pa[4]*it), f2b(pa[5]*it), f2b(pa[6]*it), f2b(pa[7]*it)};
    }
}

// ---- W1 [384,512] -> W1T bf16 [512,384]; W2 [512,128] -> W2T bf16 [128,512] ----
__global__ void conv_w(const float* __restrict__ W1, const float* __restrict__ W2,
                       __bf16* __restrict__ W1T, __bf16* __restrict__ W2T) {
    int i = blockIdx.x * 256 + threadIdx.x;
    if (i < K1 * HID) {
        int k = i / HID, n = i % HID;
        W1T[n * K1 + k] = f2b(W1[i]);
    } else {
        int j = i - K1 * HID;
        if (j < HID * OUTD) {
            int k = j / OUTD, n = j % OUTD;
            W2T[n * HID + k] = f2b(W2[j]);
        }
    }
}

// ======== fused MLP ========
// 512 threads (8 waves = 2/SIMD), BM=128, 32 phases of K=64.
// LDS 160 KB: Xs 96 (persistent, staged during nc=0), Wst 3x16 rotating
// (depth-2 counted vmcnt), HsH 16 (tanh half-buffer, wn-split writes).
// All frag/staging addresses hoisted to per-thread constants.

__global__ __launch_bounds__(512, 1) void mlp_fused(const __bf16* __restrict__ X,
                                                    const __bf16* __restrict__ W1T,
                                                    const float* __restrict__ b1,
                                                    const __bf16* __restrict__ W2T,
                                                    const float* __restrict__ b2,
                                                    float* __restrict__ out) {
    __shared__ __bf16 Xs[12 * 4096];   // 96 KB: 6 pairs of [128x32] units
    __shared__ __bf16 Wst[6 * 4096];   // 48 KB: 3 rotating 16 KB slots
    __shared__ __bf16 HsH[128 * 64];   // 16 KB: H half-chunk
    const int bm = blockIdx.x * 128;
    const int t = threadIdx.x;
    const int lane = t & 63;
    const int w = t >> 6;          // 0..7
    const int quad = lane >> 4;
    const int l16 = lane & 15;
    const int wm = w >> 2, wn = w & 3;   // wave grid 2x4: 64 rows x 32 cols

    // ---- per-thread constant addressing (hoisted out of all phases) ----
    // staging source offsets (thread t loads row r_st, swizzled col c_st)
    const int r_st = t >> 2;
    const int sw_st = (r_st & 3) ^ ((r_st >> 2) & 3);
    const int c_st = (t & 3) ^ sw_st;
    int grx = bm + r_st; if (grx >= NN) grx = NN - 1;
    const long xoff  = (long)grx * K1 + c_st * 8;
    const long w1off = (long)r_st * K1 + c_st * 8;
    const long w2off = (long)r_st * HID + c_st * 8;
    // fragment read offsets (element units)
    int aoff[4], boff[2], hoff[4][2];
    #pragma unroll
    for (int i = 0; i < 4; i++) {
        const int r = wm * 64 + i * 16 + l16;
        const int sw = (r & 3) ^ ((r >> 2) & 3);
        aoff[i] = (r * 4 + (quad ^ sw)) * 8;
        const int p0 = quad ^ (r & 3);
        const int bb = (r >> 2) & 1;
        hoff[i][0] = (r * 8 + (p0 | ((0 ^ bb) << 2))) * 8;
        hoff[i][1] = (r * 8 + (p0 | ((1 ^ bb) << 2))) * 8;
    }
    #pragma unroll
    for (int j = 0; j < 2; j++) {
        const int r = wn * 32 + j * 16 + l16;
        const int sw = (r & 3) ^ ((r >> 2) & 3);
        boff[j] = (r * 4 + (quad ^ sw)) * 8;
    }

    // biases to regs BEFORE the counted-vmcnt regime
    float b1r[4][2], b2r[2];
    #pragma unroll
    for (int nc = 0; nc < 4; nc++)
        #pragma unroll
        for (int j = 0; j < 2; j++)
            b1r[nc][j] = b1[nc * 128 + wn * 32 + j * 16 + l16];
    #pragma unroll
    for (int j = 0; j < 2; j++) b2r[j] = b2[wn * 32 + j * 16 + l16];
    asm volatile("s_waitcnt vmcnt(0)" ::: "memory");

    f32x4 oacc[4][2];
    #pragma unroll
    for (int i = 0; i < 4; i++)
        #pragma unroll
        for (int j = 0; j < 2; j++)
            #pragma unroll
            for (int r = 0; r < 4; r++) oacc[i][j][r] = 0.0f;

    // stage group g (for phase g): 2 gll16 per unit-pair per thread
    auto stage_group = [&](int g) {
        if (g >= 32) return;
        const int gn = g >> 3, gp = g & 7;
        __bf16* slot = Wst + (g % 3) * 8192;
        if (gp < 6) {
            const int k0 = gp * 64;
            if (gn == 0) {
                __bf16* xu = Xs + gp * 8192;
                gll16(X + xoff + k0,      xu + t * 8);
                gll16(X + xoff + k0 + 32, xu + 4096 + t * 8);
            }
            const long wo = w1off + (long)gn * 128 * K1 + k0;
            gll16(W1T + wo,      slot + t * 8);
            gll16(W1T + wo + 32, slot + 4096 + t * 8);
        } else {
            const long wo = w2off + gn * 128 + (gp - 6) * 64;
            gll16(W2T + wo,      slot + t * 8);
            gll16(W2T + wo + 32, slot + 4096 + t * 8);
        }
    };

    // prologue: groups 0 and 1 (nc0 kt0, kt1: X pair + W1 pair each = 4 instr)
    stage_group(0);
    stage_group(1);

    #pragma unroll
    for (int nc = 0; nc < 4; nc++) {
        f32x4 hacc[4][2];
        #pragma unroll
        for (int i = 0; i < 4; i++)
            #pragma unroll
            for (int j = 0; j < 2; j++)
                #pragma unroll
                for (int r = 0; r < 4; r++) hacc[i][j][r] = 0.0f;

        // ---- 6 kt phases (K=64 each) ----
        #pragma unroll
        for (int kt = 0; kt < 6; kt++) {
            const int p = nc * 8 + kt;
            if (p < 5) sync_v4(); else sync_v2();
            const __bf16* xu = Xs + kt * 8192;
            const __bf16* slot = Wst + (p % 3) * 8192;
            bf16x8 a0[4], a1[4], bw0[2], bw1[2];
            #pragma unroll
            for (int i = 0; i < 4; i++) {
                a0[i] = *(const bf16x8*)(xu + aoff[i]);
                a1[i] = *(const bf16x8*)(xu + 4096 + aoff[i]);
            }
            #pragma unroll
            for (int j = 0; j < 2; j++) {
                bw0[j] = *(const bf16x8*)(slot + boff[j]);
                bw1[j] = *(const bf16x8*)(slot + 4096 + boff[j]);
            }
            stage_group(p + 2);
            __builtin_amdgcn_s_setprio(1);
            #pragma unroll
            for (int i = 0; i < 4; i++)
                #pragma unroll
                for (int j = 0; j < 2; j++)
                    hacc[i][j] = __builtin_amdgcn_mfma_f32_16x16x32_bf16(a0[i], bw0[j], hacc[i][j], 0, 0, 0);
            #pragma unroll
            for (int i = 0; i < 4; i++)
                #pragma unroll
                for (int j = 0; j < 2; j++)
                    hacc[i][j] = __builtin_amdgcn_mfma_f32_16x16x32_bf16(a1[i], bw1[j], hacc[i][j], 0, 0, 0);
            __builtin_amdgcn_s_setprio(0);
        }

        // ---- tanh half0 (H cols 0..63, owned by waves wn<2) ----
        if (wn < 2) {
            #pragma unroll
            for (int j = 0; j < 2; j++) {
                const int cl = wn * 32 + j * 16 + l16;
                const int ch = cl >> 3;
                const float bb = b1r[nc][j];
                #pragma unroll
                for (int i = 0; i < 4; i++) {
                    const int rb = wm * 64 + i * 16 + quad * 4;
                    #pragma unroll
                    for (int r = 0; r < 4; r++) {
                        const int rr = rb + r;
                        const int pch = ((ch & 3) ^ (rr & 3)) | ((((ch >> 2) ^ (rr >> 2)) & 1) << 2);
                        HsH[(rr * 8 + pch) * 8 + (cl & 7)] = f2b(ftanh(hacc[i][j][r] + bb));
                    }
                }
            }
        }
        sync_lgkm_v2();   // phase p = nc*8+6 entry

        // ---- kk0 phase: O += tanh(H)[:,0:64] @ W2T-slice ----
        {
            const int p = nc * 8 + 6;
            const __bf16* slot = Wst + (p % 3) * 8192;
            bf16x8 ah[4][2], bh[2][2];
            #pragma unroll
            for (int i = 0; i < 4; i++) {
                ah[i][0] = *(const bf16x8*)(HsH + hoff[i][0]);
                ah[i][1] = *(const bf16x8*)(HsH + hoff[i][1]);
            }
            #pragma unroll
            for (int j = 0; j < 2; j++) {
                bh[j][0] = *(const bf16x8*)(slot + boff[j]);
                bh[j][1] = *(const bf16x8*)(slot + 4096 + boff[j]);
            }
            stage_group(p + 2);
            __builtin_amdgcn_s_setprio(1);
            #pragma unroll
            for (int u = 0; u < 2; u++)
                #pragma unroll
                for (int i = 0; i < 4; i++)
                    #pragma unroll
                    for (int j = 0; j < 2; j++)
                        oacc[i][j] = __builtin_amdgcn_mfma_f32_16x16x32_bf16(ah[i][u], bh[j][u], oacc[i][j], 0, 0, 0);
            __builtin_amdgcn_s_setprio(0);
        }
        bar_only();   // kk0 readers done before half1 overwrite

        // ---- tanh half1 (H cols 64..127, owned by waves wn>=2) ----
        if (wn >= 2) {
            #pragma unroll
            for (int j = 0; j < 2; j++) {
                const int cl = (wn - 2) * 32 + j * 16 + l16;
                const int ch = cl >> 3;
                const float bb = b1r[nc][j];
                #pragma unroll
                for (int i = 0; i < 4; i++) {
                    const int rb = wm * 64 + i * 16 + quad * 4;
                    #pragma unroll
                    for (int r = 0; r < 4; r++) {
                        const int rr = rb + r;
                        const int pch = ((ch & 3) ^ (rr & 3)) | ((((ch >> 2) ^ (rr >> 2)) & 1) << 2);
                        HsH[(rr * 8 + pch) * 8 + (cl & 7)] = f2b(ftanh(hacc[i][j][r] + bb));
                    }
                }
            }
        }
        if (nc == 3) sync_lgkm_v0(); else sync_lgkm_v2();   // phase p = nc*8+7 entry

        // ---- kk1 phase: O += tanh(H)[:,64:128] @ W2T-slice ----
        {
            const int p = nc * 8 + 7;
            const __bf16* slot = Wst + (p % 3) * 8192;
            bf16x8 ah[4][2], bh[2][2];
            #pragma unroll
            for (int i = 0; i < 4; i++) {
                ah[i][0] = *(const bf16x8*)(HsH + hoff[i][0]);
                ah[i][1] = *(const bf16x8*)(HsH + hoff[i][1]);
            }
            #pragma unroll
            for (int j = 0; j < 2; j++) {
                bh[j][0] = *(const bf16x8*)(slot + boff[j]);
                bh[j][1] = *(const bf16x8*)(slot + 4096 + boff[j]);
            }
            stage_group(p + 2);
            __builtin_amdgcn_s_setprio(1);
            #pragma unroll
            for (int u = 0; u < 2; u++)
                #pragma unroll
                for (int i = 0; i < 4; i++)
                    #pragma unroll
                    for (int j = 0; j < 2; j++)
                        oacc[i][j] = __builtin_amdgcn_mfma_f32_16x16x32_bf16(ah[i][u], bh[j][u], oacc[i][j], 0, 0, 0);
            __builtin_amdgcn_s_setprio(0);
        }
    }

    // epilogue: out f32 [NN x 128]
    #pragma unroll
    for (int i = 0; i < 4; i++) {
        #pragma unroll
        for (int r = 0; r < 4; r++) {
            const int gr = bm + wm * 64 + i * 16 + quad * 4 + r;
            if (gr < NN) {
                float* orow = out + (long)gr * OUTD + wn * 32 + l16;
                orow[0]  = oacc[i][0][r] + b2r[0];
                orow[16] = oacc[i][1][r] + b2r[1];
            }
        }
    }
}

extern "C" void kernel_launch(void* const* d_in, const int* in_sizes, int n_in,
                              void* d_out, int out_size, void* d_ws, size_t ws_size,
                              hipStream_t stream) {
    const float* news  = (const float*)d_in[0];
    const float* ent_f = (const float*)d_in[1];
    const float* top_f = (const float*)d_in[2];
    const int* ent_row = (const int*)d_in[3];
    const int* ent_col = (const int*)d_in[4];
    const int* top_row = (const int*)d_in[5];
    const int* top_col = (const int*)d_in[6];
    const float* W1 = (const float*)d_in[7];
    const float* b1 = (const float*)d_in[8];
    const float* W2 = (const float*)d_in[9];
    const float* b2 = (const float*)d_in[10];

    char* ws = (char*)d_ws;
    int* offs_e = (int*)(ws + 0);
    int* offs_t = (int*)(ws + 400016);
    int* bc_e   = (int*)(ws + 800032);
    int* bc_t   = (int*)(ws + 801596);
    int* cur_e  = (int*)(ws + 803160);
    int* cur_t  = (int*)(ws + 804724);
    int* be     = (int*)(ws + 806320);
    int* bt     = (int*)(ws + 7206320);
    int* se     = (int*)(ws + 13606320);
    int* st     = (int*)(ws + 20006320);
    __bf16* entb = (__bf16*)(ws + 26406336);
    __bf16* topb = (__bf16*)(ws + 39206336);
    __bf16* X   = (__bf16*)(ws + 102400000);
    __bf16* W1T = (__bf16*)(ws + 179200000);
    __bf16* W2T = (__bf16*)(ws + 179593216);

    hipMemsetAsync(ws + 800032, 0, 6256, stream);   // zero bc/cur arrays
    conv_w<<<1024, 256, 0, stream>>>(W1, W2, W1T, W2T);
    conv_feats<<<19000, 256, 0, stream>>>(ent_f, top_f, news, entb, topb, X);
    hist_buckets<<<196, 256, 0, stream>>>(ent_row, top_row, bc_e, bc_t);
    scan_buckets<<<dim3(1, 2), 512, 0, stream>>>(bc_e, bc_t, cur_e, cur_t, offs_e, offs_t);
    scatter_bucket<<<392, 256, 0, stream>>>(ent_row, ent_col, top_row, top_col,
                                            cur_e, cur_t, be, bt);
    bucket_csr<<<dim3(NBKT, 2), 256, 0, stream>>>(be, bt, bc_e, bc_t,
                                                  offs_e, offs_t, se, st);
    aggregate2<<<NN / 4, 256, 0, stream>>>(entb, topb, offs_e, offs_t, se, st, X);
    mlp_fused<<<782, 512, 0, stream>>>(X, W1T, b1, W2T, b2, (float*)d_out);
}

// Round 11
// 527.101 us; speedup vs baseline: 1.0213x; 1.0213x over previous
//
#include <hip/hip_runtime.h>
#include <hip/hip_bf16.h>

#define NN 100000
#define NE 50000
#define NT 2000
#define DD 128
#define NEDGE 1600000
#define HID 512
#define OUTD 128
#define K1 (3*DD)   // 384: X layout [news | ent_agg | top_agg]
#define NBKT 391    // ceil(100000/256) buckets of 256 nodes

typedef __bf16 bf16x8 __attribute__((ext_vector_type(8)));
typedef __bf16 bf16x4 __attribute__((ext_vector_type(4)));
typedef float  f32x4  __attribute__((ext_vector_type(4)));

__device__ __forceinline__ __bf16 f2b(float f) {
    __hip_bfloat16 h = __float2bfloat16(f);
    union { __hip_bfloat16 h; __bf16 b; } u; u.h = h; return u.b;
}

__device__ __forceinline__ void gll16(const void* g, void* l) {
    __builtin_amdgcn_global_load_lds((const __attribute__((address_space(1))) void*)g,
                                     (__attribute__((address_space(3))) void*)l, 16, 0, 0);
}

__device__ __forceinline__ float ftanh(float x) {
    x = fminf(fmaxf(x, -15.f), 15.f);
    float t = __expf(2.f * x);
    return (t - 1.f) / (t + 1.f);
}

__device__ __forceinline__ void bar_only() { asm volatile("s_barrier" ::: "memory"); }

// ---- convert: ent/top tables -> bf16 tables; news -> bf16 into X cols 0..127 ----
__global__ void conv_feats(const float* __restrict__ entf, const float* __restrict__ topf,
                           const float* __restrict__ news,
                           __bf16* __restrict__ entb, __bf16* __restrict__ topb,
                           __bf16* __restrict__ X) {
    long i = ((long)blockIdx.x * 256 + threadIdx.x) * 4;
    const long NEL = (long)NE * DD;            // 6.4M
    const long NTL = (long)NT * DD;            // 0.256M
    if (i < NEL) {
        float4 v = *(const float4*)(entf + i);
        *(bf16x4*)(entb + i) = bf16x4{f2b(v.x), f2b(v.y), f2b(v.z), f2b(v.w)};
    } else if (i < NEL + NTL) {
        long j = i - NEL;
        float4 v = *(const float4*)(topf + j);
        *(bf16x4*)(topb + j) = bf16x4{f2b(v.x), f2b(v.y), f2b(v.z), f2b(v.w)};
    } else {
        long j = i - NEL - NTL;                // 0 .. 12.8M
        long row = j >> 7, col = j & 127;      // news [NN x 128], 4-aligned col
        float4 v = *(const float4*)(news + j);
        *(bf16x4*)(X + row * K1 + col) = bf16x4{f2b(v.x), f2b(v.y), f2b(v.z), f2b(v.w)};
    }
}

// ---- bucket histogram ----
__global__ __launch_bounds__(256) void hist_buckets(const int* __restrict__ er,
                                                    const int* __restrict__ tr,
                                                    int* __restrict__ bc_e,
                                                    int* __restrict__ bc_t) {
    __shared__ int lhe[NBKT], lht[NBKT];
    const int tid = threadIdx.x;
    for (int i = tid; i < NBKT; i += 256) { lhe[i] = 0; lht[i] = 0; }
    __syncthreads();
    const int base = blockIdx.x * 8192;
    #pragma unroll 4
    for (int k = 0; k < 32; k++) {
        int e = base + k * 256 + tid;
        if (e < NEDGE) {
            atomicAdd(&lhe[er[e] >> 8], 1);
            atomicAdd(&lht[tr[e] >> 8], 1);
        }
    }
    __syncthreads();
    for (int i = tid; i < NBKT; i += 256) {
        if (lhe[i]) atomicAdd(&bc_e[i], lhe[i]);
        if (lht[i]) atomicAdd(&bc_t[i], lht[i]);
    }
}

// ---- scan 391 bucket counts ----
__global__ void scan_buckets(int* __restrict__ bc_e, int* __restrict__ bc_t,
                             int* __restrict__ cur_e, int* __restrict__ cur_t,
                             int* __restrict__ offs_e, int* __restrict__ offs_t) {
    int* bc  = blockIdx.y ? bc_t : bc_e;
    int* cur = blockIdx.y ? cur_t : cur_e;
    int* offs = blockIdx.y ? offs_t : offs_e;
    __shared__ int s[512];
    int i = threadIdx.x;
    s[i] = (i < NBKT) ? bc[i] : 0;
    __syncthreads();
    #pragma unroll
    for (int off = 1; off < 512; off <<= 1) {
        int v = (i >= off) ? s[i - off] : 0;
        __syncthreads();
        s[i] += v;
        __syncthreads();
    }
    if (i < NBKT) {
        bc[i] = s[i];
        cur[i] = i ? s[i - 1] : 0;
    }
    if (i == 0) offs[0] = 0;
}

// ---- partition edges into buckets ----
__global__ __launch_bounds__(256) void scatter_bucket(const int* __restrict__ er,
                                                      const int* __restrict__ ec,
                                                      const int* __restrict__ tr,
                                                      const int* __restrict__ tc,
                                                      int* __restrict__ cur_e,
                                                      int* __restrict__ cur_t,
                                                      int* __restrict__ be,
                                                      int* __restrict__ bt) {
    __shared__ int lhe[NBKT], lht[NBKT];
    __shared__ int lbe[NBKT], lbt[NBKT];
    const int tid = threadIdx.x;
    for (int i = tid; i < NBKT; i += 256) { lhe[i] = 0; lht[i] = 0; }
    __syncthreads();
    const int base = blockIdx.x * 4096;
    #pragma unroll 4
    for (int k = 0; k < 16; k++) {
        int e = base + k * 256 + tid;
        if (e < NEDGE) {
            atomicAdd(&lhe[er[e] >> 8], 1);
            atomicAdd(&lht[tr[e] >> 8], 1);
        }
    }
    __syncthreads();
    for (int i = tid; i < NBKT; i += 256) {
        int c = lhe[i];
        lbe[i] = c ? atomicAdd(&cur_e[i], c) : 0;
        lhe[i] = 0;
        c = lht[i];
        lbt[i] = c ? atomicAdd(&cur_t[i], c) : 0;
        lht[i] = 0;
    }
    __syncthreads();
    #pragma unroll 4
    for (int k = 0; k < 16; k++) {
        int e = base + k * 256 + tid;
        if (e < NEDGE) {
            int r = er[e];
            int b = r >> 8;
            int p = lbe[b] + atomicAdd(&lhe[b], 1);
            be[p] = ((r & 255) << 16) | ec[e];
            r = tr[e];
            b = r >> 8;
            p = lbt[b] + atomicAdd(&lht[b], 1);
            bt[p] = ((r & 255) << 16) | tc[e];
        }
    }
}

// ---- per-bucket exact CSR ----
__global__ __launch_bounds__(256) void bucket_csr(const int* __restrict__ be,
                                                  const int* __restrict__ bt,
                                                  const int* __restrict__ bc_e,
                                                  const int* __restrict__ bc_t,
                                                  int* __restrict__ offs_e,
                                                  int* __restrict__ offs_t,
                                                  int* __restrict__ se,
                                                  int* __restrict__ st) {
    const int* buf = blockIdx.y ? bt : be;
    const int* bc  = blockIdx.y ? bc_t : bc_e;
    int* offs      = blockIdx.y ? offs_t : offs_e;
    int* sout      = blockIdx.y ? st : se;
    const int b = blockIdx.x;
    const int tid = threadIdx.x;
    const int start = b ? bc[b - 1] : 0;
    const int cnt = bc[b] - start;

    __shared__ int scn[256];
    __shared__ int lcur[256];
    scn[tid] = 0;
    __syncthreads();
    for (int i = tid; i < cnt; i += 256)
        atomicAdd(&scn[buf[start + i] >> 16], 1);
    __syncthreads();
    #pragma unroll
    for (int off = 1; off < 256; off <<= 1) {
        int v = (tid >= off) ? scn[tid - off] : 0;
        __syncthreads();
        scn[tid] += v;
        __syncthreads();
    }
    const int node = b * 256 + tid;
    if (node < NN) offs[node + 1] = start + scn[tid];
    lcur[tid] = start + (tid ? scn[tid - 1] : 0);
    __syncthreads();
    for (int i = tid; i < cnt; i += 256) {
        int v = buf[start + i];
        int p = atomicAdd(&lcur[v >> 16], 1);
        sout[p] = v & 0xFFFF;
    }
}

// ---- gather-aggregate (bf16 tables) -> X cols 128..383 ----
__global__ __launch_bounds__(256) void aggregate2(const __bf16* __restrict__ entb,
                                                  const __bf16* __restrict__ topb,
                                                  const int* __restrict__ offs_e,
                                                  const int* __restrict__ offs_t,
                                                  const int* __restrict__ se,
                                                  const int* __restrict__ st,
                                                  __bf16* __restrict__ X) {
    const int wave = threadIdx.x >> 6, lane = threadIdx.x & 63;
    const int node = blockIdx.x * 4 + wave;
    if (node >= NN) return;
    const int h = lane >> 4;        // 0..3: edge phase
    const int d = (lane & 15) * 8;  // dim group of 8

    float ea[8] = {0,0,0,0,0,0,0,0};
    float pa[8] = {0,0,0,0,0,0,0,0};

    const int s0 = offs_e[node], s1 = offs_e[node + 1];
    int i = s0 + h;
    for (; i + 12 < s1; i += 16) {
        int c0 = se[i], c1 = se[i + 4], c2 = se[i + 8], c3 = se[i + 12];
        bf16x8 v0 = *(const bf16x8*)(entb + (long)c0 * DD + d);
        bf16x8 v1 = *(const bf16x8*)(entb + (long)c1 * DD + d);
        bf16x8 v2 = *(const bf16x8*)(entb + (long)c2 * DD + d);
        bf16x8 v3 = *(const bf16x8*)(entb + (long)c3 * DD + d);
        #pragma unroll
        for (int j = 0; j < 8; j++)
            ea[j] += ((float)v0[j] + (float)v1[j]) + ((float)v2[j] + (float)v3[j]);
    }
    for (; i < s1; i += 4) {
        bf16x8 v = *(const bf16x8*)(entb + (long)se[i] * DD + d);
        #pragma unroll
        for (int j = 0; j < 8; j++) ea[j] += (float)v[j];
    }

    const int t0 = offs_t[node], t1 = offs_t[node + 1];
    i = t0 + h;
    for (; i + 12 < t1; i += 16) {
        int c0 = st[i], c1 = st[i + 4], c2 = st[i + 8], c3 = st[i + 12];
        bf16x8 v0 = *(const bf16x8*)(topb + (long)c0 * DD + d);
        bf16x8 v1 = *(const bf16x8*)(topb + (long)c1 * DD + d);
        bf16x8 v2 = *(const bf16x8*)(topb + (long)c2 * DD + d);
        bf16x8 v3 = *(const bf16x8*)(topb + (long)c3 * DD + d);
        #pragma unroll
        for (int j = 0; j < 8; j++)
            pa[j] += ((float)v0[j] + (float)v1[j]) + ((float)v2[j] + (float)v3[j]);
    }
    for (; i < t1; i += 4) {
        bf16x8 v = *(const bf16x8*)(topb + (long)st[i] * DD + d);
        #pragma unroll
        for (int j = 0; j < 8; j++) pa[j] += (float)v[j];
    }

    #pragma unroll
    for (int j = 0; j < 8; j++) {
        ea[j] += __shfl_xor(ea[j], 16, 64);
        ea[j] += __shfl_xor(ea[j], 32, 64);
        pa[j] += __shfl_xor(pa[j], 16, 64);
        pa[j] += __shfl_xor(pa[j], 32, 64);
    }

    const float ie = 1.0f / ((float)(s1 - s0) + 1e-8f);
    const float it = 1.0f / ((float)(t1 - t0) + 1e-8f);
    __bf16* xr = X + (long)node * K1;
    if (h == 1) {
        *(bf16x8*)(xr + DD + d) = bf16x8{f2b(ea[0]*ie), f2b(ea[1]*ie), f2b(ea[2]*ie), f2b(ea[3]*ie),
                                         f2b(ea[4]*ie), f2b(ea[5]*ie), f2b(ea[6]*ie), f2b(ea[7]*ie)};
    } else if (h == 2) {
        *(bf16x8*)(xr + 2*DD + d) = bf16x8{f2b(pa[0]*it), f2b(pa[1]*it), f2b(pa[2]*it), f2b(pa[3]*it),
                                           f2b(pa[4]*it), f2b(pa[5]*it), f2b(pa[6]*it), f2b(pa[7]*it)};
    }
}

// ---- W1 [384,512] -> W1T bf16 [512,384]; W2 [512,128] -> W2T bf16 [128,512] ----
__global__ void conv_w(const float* __restrict__ W1, const float* __restrict__ W2,
                       __bf16* __restrict__ W1T, __bf16* __restrict__ W2T) {
    int i = blockIdx.x * 256 + threadIdx.x;
    if (i < K1 * HID) {
        int k = i / HID, n = i % HID;
        W1T[n * K1 + k] = f2b(W1[i]);
    } else {
        int j = i - K1 * HID;
        if (j < HID * OUTD) {
            int k = j / OUTD, n = j % OUTD;
            W2T[n * HID + k] = f2b(W2[j]);
        }
    }
}

// ======== fused MLP, loop-interchanged ========
// BM=64, 256 threads (4 waves, grid 2x2). nc INNER: per K-step (12 phases of
// K=32) stage X tile once + full W1T K-slice [512x32]; 32 MFMA/wave/phase into
// hacc[4][2][4]. Then GEMM2: 8 phases of 16 MFMA (Hs + rotating W2 slots reuse
// the W region). X: 3-buf depth-2 (HBM); W1: 2-buf depth-1 (L2); fixed issue
// order W1(p+1),X(p+2) makes the per-phase wait exactly vmcnt(1).

// stage a [128 x 32] bf16 tile (swizzled); 2 gll16 per thread (256 thr)
__device__ __forceinline__ void stage_tile(const __bf16* __restrict__ src, int ldK,
                                           int k0, int row0, int rowmax,
                                           __bf16* lds, int w, int lane) {
    #pragma unroll
    for (int half = 0; half < 2; half++) {
        int ss = w * 64 + half * 256 + lane;
        int r = ss >> 2;
        int sw = (r & 3) ^ ((r >> 2) & 3);
        int c = (ss & 3) ^ sw;
        int gr = row0 + r; if (gr >= rowmax) gr = rowmax - 1;
        gll16(src + (long)gr * ldK + k0 + c * 8,
              lds + (w * 64 + half * 256) * 8);
    }
}

// read fragment (logical row r, k-chunk q) from swizzled [Rx32] tile
__device__ __forceinline__ bf16x8 frag(const __bf16* lds, int r, int q) {
    int sw = (r & 3) ^ ((r >> 2) & 3);
    return *(const bf16x8*)(lds + (r * 4 + (q ^ sw)) * 8);
}

// Hs [64 rows x 128 k] swizzled (same formulas as verified 128x128 version)
__device__ __forceinline__ void hs_write(__bf16* Hs, int r, int c, __bf16 v) {
    int ch = c >> 3;
    int pch = ((((ch >> 2) ^ ((r >> 2) & 3)) << 2) | ((ch & 3) ^ (r & 3)));
    Hs[(r * 16 + pch) * 8 + (c & 7)] = v;
}
__device__ __forceinline__ bf16x8 hs_frag(const __bf16* Hs, int r, int kk, int q) {
    int pch = (((kk ^ ((r >> 2) & 3)) << 2) | (q ^ (r & 3)));
    return *(const bf16x8*)(Hs + (r * 16 + pch) * 8);
}

__global__ __launch_bounds__(256) void mlp_fused(const __bf16* __restrict__ X,
                                                 const __bf16* __restrict__ W1T,
                                                 const float* __restrict__ b1,
                                                 const __bf16* __restrict__ W2T,
                                                 const float* __restrict__ b2,
                                                 float* __restrict__ out) {
    __shared__ __bf16 Xs[3][2048];    // 3 x 4 KB (X [64x32] tiles, depth-2)
    __shared__ __bf16 Wreg[8][4096];  // 64 KB: GEMM1 2x[512x32]; GEMM2 Hs+3 W2 slots
    const int bm = blockIdx.x * 64;
    const int t = threadIdx.x;
    const int lane = t & 63;
    const int w = t >> 6;              // 0..3
    const int quad = lane >> 4;
    const int l16 = lane & 15;
    const int wm = w >> 1, wn = w & 1; // wave grid 2x2: 32 rows x (64 cols/chunk)

    // ---- hoisted addressing ----
    // X staging: thread t -> slot t (row t>>2, swizzled col)
    const int r_sx = t >> 2;
    const int sw_sx = (r_sx & 3) ^ ((r_sx >> 2) & 3);
    const int c_sx = (t & 3) ^ sw_sx;
    int grx = bm + r_sx; if (grx >= NN) grx = NN - 1;
    const long xsrc = (long)grx * K1 + c_sx * 8;
    // frag offsets
    int aoff[2], boff[4];
    #pragma unroll
    for (int i = 0; i < 2; i++) {
        const int r = wm * 32 + i * 16 + l16;
        const int sw = (r & 3) ^ ((r >> 2) & 3);
        aoff[i] = (r * 4 + (quad ^ sw)) * 8;
    }
    #pragma unroll
    for (int j = 0; j < 4; j++) {
        const int r = wn * 64 + j * 16 + l16;
        const int sw = (r & 3) ^ ((r >> 2) & 3);
        boff[j] = (r * 4 + (quad ^ sw)) * 8;
    }

    // biases to regs BEFORE the counted-vmcnt regime
    float b1r[4][4], b2r[4];
    #pragma unroll
    for (int nc = 0; nc < 4; nc++)
        #pragma unroll
        for (int j = 0; j < 4; j++)
            b1r[nc][j] = b1[nc * 128 + wn * 64 + j * 16 + l16];
    #pragma unroll
    for (int j = 0; j < 4; j++) b2r[j] = b2[wn * 64 + j * 16 + l16];
    asm volatile("s_waitcnt vmcnt(0)" ::: "memory");

    f32x4 hacc[4][2][4];   // [nc][i][j]
    #pragma unroll
    for (int nc = 0; nc < 4; nc++)
        #pragma unroll
        for (int i = 0; i < 2; i++)
            #pragma unroll
            for (int j = 0; j < 4; j++)
                #pragma unroll
                for (int r = 0; r < 4; r++) hacc[nc][i][j][r] = 0.0f;

    // prologue (FIFO: X0, W1_0(8), X1): phase-0 wait vmcnt(1) drains X0+W1_0
    gll16(X + xsrc, &Xs[0][0] + t * 8);
    #pragma unroll
    for (int nc = 0; nc < 4; nc++)
        stage_tile(W1T, K1, 0, nc * 128, HID, &Wreg[nc][0], w, lane);
    gll16(X + xsrc + 32, &Xs[1][0] + t * 8);

    // ---- GEMM1: 12 phases of K=32, 32 MFMA/wave each ----
    #pragma unroll
    for (int kt = 0; kt < 12; kt++) {
        if (kt < 11) asm volatile("s_waitcnt vmcnt(1)\n\ts_barrier" ::: "memory");
        else         asm volatile("s_waitcnt vmcnt(0)\n\ts_barrier" ::: "memory");
        const __bf16* xb = &Xs[kt % 3][0];
        const __bf16* wb = &Wreg[(kt & 1) * 4][0];
        bf16x8 a0 = *(const bf16x8*)(xb + aoff[0]);
        bf16x8 a1 = *(const bf16x8*)(xb + aoff[1]);
        // issue order: W1(kt+1) first, then X(kt+2)  -> vmcnt(1) works
        if (kt < 11) {
            __bf16* wnx = &Wreg[((kt + 1) & 1) * 4][0];
            #pragma unroll
            for (int nc = 0; nc < 4; nc++)
                stage_tile(W1T, K1, (kt + 1) * 32, nc * 128, HID, wnx + nc * 4096, w, lane);
        }
        if (kt < 10)
            gll16(X + xsrc + (kt + 2) * 32, &Xs[(kt + 2) % 3][0] + t * 8);
        __builtin_amdgcn_s_setprio(1);
        #pragma unroll
        for (int nc = 0; nc < 4; nc++) {
            bf16x8 bw[4];
            #pragma unroll
            for (int j = 0; j < 4; j++)
                bw[j] = *(const bf16x8*)(wb + nc * 4096 + boff[j]);
            #pragma unroll
            for (int i = 0; i < 2; i++) {
                bf16x8 av = i ? a1 : a0;
                #pragma unroll
                for (int j = 0; j < 4; j++)
                    hacc[nc][i][j] = __builtin_amdgcn_mfma_f32_16x16x32_bf16(av, bw[j], hacc[nc][i][j], 0, 0, 0);
            }
        }
        __builtin_amdgcn_s_setprio(0);
    }

    f32x4 oacc[2][4];
    #pragma unroll
    for (int i = 0; i < 2; i++)
        #pragma unroll
        for (int j = 0; j < 4; j++)
            #pragma unroll
            for (int r = 0; r < 4; r++) oacc[i][j][r] = 0.0f;

    // ---- GEMM2: reuse W region. Hs = Wreg[0..1] (16 KB); W2 slots s=0..2 at
    // Wreg[2+2s], Wreg[3+2s]. 8 phases (4 nc x 2 of K=64), depth-2 vmcnt(4). ----
    __bf16* Hs = &Wreg[0][0];
    bar_only();   // all GEMM1 reads complete before region reuse

    auto stage_w2 = [&](int g) {   // 4 gll16
        const int ncg = g >> 1, half = g & 1, s = g % 3;
        stage_tile(W2T, HID, ncg * 128 + half * 64,      0, OUTD, &Wreg[2 + 2 * s][0], w, lane);
        stage_tile(W2T, HID, ncg * 128 + half * 64 + 32, 0, OUTD, &Wreg[3 + 2 * s][0], w, lane);
    };
    stage_w2(0);
    stage_w2(1);

    #pragma unroll
    for (int nc = 0; nc < 4; nc++) {
        if (nc > 0) bar_only();   // prior phase's Hs readers done before overwrite
        // tanh(hacc[nc]) -> Hs
        #pragma unroll
        for (int j = 0; j < 4; j++) {
            const int cl = wn * 64 + j * 16 + l16;
            const float bb = b1r[nc][j];
            #pragma unroll
            for (int i = 0; i < 2; i++) {
                const int rb = wm * 32 + i * 16 + quad * 4;
                #pragma unroll
                for (int r = 0; r < 4; r++)
                    hs_write(Hs, rb + r, cl, f2b(ftanh(hacc[nc][i][j][r] + bb)));
            }
        }
        #pragma unroll
        for (int p2 = 0; p2 < 2; p2++) {
            const int q = nc * 2 + p2;
            if (q < 7) asm volatile("s_waitcnt lgkmcnt(0) vmcnt(4)\n\ts_barrier" ::: "memory");
            else       asm volatile("s_waitcnt lgkmcnt(0) vmcnt(0)\n\ts_barrier" ::: "memory");
            const __bf16* s0 = &Wreg[2 + 2 * (q % 3)][0];
            bf16x8 ah[2][2], bh[4][2];
            #pragma unroll
            for (int i = 0; i < 2; i++) {
                const int rr = wm * 32 + i * 16 + l16;
                ah[i][0] = hs_frag(Hs, rr, p2 * 2 + 0, quad);
                ah[i][1] = hs_frag(Hs, rr, p2 * 2 + 1, quad);
            }
            #pragma unroll
            for (int j = 0; j < 4; j++) {
                bh[j][0] = *(const bf16x8*)(s0 + boff[j]);
                bh[j][1] = *(const bf16x8*)(s0 + 4096 + boff[j]);
            }
            if (q < 6) stage_w2(q + 2);
            __builtin_amdgcn_s_setprio(1);
            #pragma unroll
            for (int u = 0; u < 2; u++)
                #pragma unroll
                for (int i = 0; i < 2; i++)
                    #pragma unroll
                    for (int j = 0; j < 4; j++)
                        oacc[i][j] = __builtin_amdgcn_mfma_f32_16x16x32_bf16(ah[i][u], bh[j][u], oacc[i][j], 0, 0, 0);
            __builtin_amdgcn_s_setprio(0);
        }
    }

    // epilogue: out f32 [NN x 128]
    #pragma unroll
    for (int i = 0; i < 2; i++) {
        #pragma unroll
        for (int r = 0; r < 4; r++) {
            const int gr = bm + wm * 32 + i * 16 + quad * 4 + r;
            if (gr < NN) {
                float* orow = out + (long)gr * OUTD + wn * 64 + l16;
                #pragma unroll
                for (int j = 0; j < 4; j++)
                    orow[j * 16] = oacc[i][j][r] + b2r[j];
            }
        }
    }
}

extern "C" void kernel_launch(void* const* d_in, const int* in_sizes, int n_in,
                              void* d_out, int out_size, void* d_ws, size_t ws_size,
                              hipStream_t stream) {
    const float* news  = (const float*)d_in[0];
    const float* ent_f = (const float*)d_in[1];
    const float* top_f = (const float*)d_in[2];
    const int* ent_row = (const int*)d_in[3];
    const int* ent_col = (const int*)d_in[4];
    const int* top_row = (const int*)d_in[5];
    const int* top_col = (const int*)d_in[6];
    const float* W1 = (const float*)d_in[7];
    const float* b1 = (const float*)d_in[8];
    const float* W2 = (const float*)d_in[9];
    const float* b2 = (const float*)d_in[10];

    char* ws = (char*)d_ws;
    int* offs_e = (int*)(ws + 0);
    int* offs_t = (int*)(ws + 400016);
    int* bc_e   = (int*)(ws + 800032);
    int* bc_t   = (int*)(ws + 801596);
    int* cur_e  = (int*)(ws + 803160);
    int* cur_t  = (int*)(ws + 804724);
    int* be     = (int*)(ws + 806320);
    int* bt     = (int*)(ws + 7206320);
    int* se     = (int*)(ws + 13606320);
    int* st     = (int*)(ws + 20006320);
    __bf16* entb = (__bf16*)(ws + 26406336);
    __bf16* topb = (__bf16*)(ws + 39206336);
    __bf16* X   = (__bf16*)(ws + 102400000);
    __bf16* W1T = (__bf16*)(ws + 179200000);
    __bf16* W2T = (__bf16*)(ws + 179593216);

    hipMemsetAsync(ws + 800032, 0, 6256, stream);   // zero bc/cur arrays
    conv_w<<<1024, 256, 0, stream>>>(W1, W2, W1T, W2T);
    conv_feats<<<19000, 256, 0, stream>>>(ent_f, top_f, news, entb, topb, X);
    hist_buckets<<<196, 256, 0, stream>>>(ent_row, top_row, bc_e, bc_t);
    scan_buckets<<<dim3(1, 2), 512, 0, stream>>>(bc_e, bc_t, cur_e, cur_t, offs_e, offs_t);
    scatter_bucket<<<392, 256, 0, stream>>>(ent_row, ent_col, top_row, top_col,
                                            cur_e, cur_t, be, bt);
    bucket_csr<<<dim3(NBKT, 2), 256, 0, stream>>>(be, bt, bc_e, bc_t,
                                                  offs_e, offs_t, se, st);
    aggregate2<<<NN / 4, 256, 0, stream>>>(entb, topb, offs_e, offs_t, se, st, X);
    mlp_fused<<<1563, 256, 0, stream>>>(X, W1T, b1, W2T, b2, (float*)d_out);
}

// Round 13
// 493.271 us; speedup vs baseline: 1.0913x; 1.0686x over previous
//
#include <hip/hip_runtime.h>
#include <hip/hip_bf16.h>

#define NN 100000
#define NE 50000
#define NT 2000
#define DD 128
#define NEDGE 1600000
#define HID 512
#define OUTD 128
#define K1 (3*DD)   // 384: X layout [news | ent_agg | top_agg]
#define NBKT 391    // ceil(100000/256) buckets of 256 nodes
#define ECAP 4608   // fixed bucket capacity: mean 4096 + 8 sigma

typedef __bf16 bf16x8 __attribute__((ext_vector_type(8)));
typedef __bf16 bf16x4 __attribute__((ext_vector_type(4)));
typedef float  f32x4  __attribute__((ext_vector_type(4)));

__device__ __forceinline__ __bf16 f2b(float f) {
    __hip_bfloat16 h = __float2bfloat16(f);
    union { __hip_bfloat16 h; __bf16 b; } u; u.h = h; return u.b;
}

__device__ __forceinline__ void gll16(const void* g, void* l) {
    __builtin_amdgcn_global_load_lds((const __attribute__((address_space(1))) void*)g,
                                     (__attribute__((address_space(3))) void*)l, 16, 0, 0);
}

__device__ __forceinline__ float ftanh(float x) {
    x = fminf(fmaxf(x, -15.f), 15.f);
    float t = __expf(2.f * x);
    return (t - 1.f) / (t + 1.f);
}

// ---- convert: ent/top tables -> bf16 tables; news -> bf16 into X cols 0..127 ----
__global__ void conv_feats(const float* __restrict__ entf, const float* __restrict__ topf,
                           const float* __restrict__ news,
                           __bf16* __restrict__ entb, __bf16* __restrict__ topb,
                           __bf16* __restrict__ X) {
    long i = ((long)blockIdx.x * 256 + threadIdx.x) * 4;
    const long NEL = (long)NE * DD;            // 6.4M
    const long NTL = (long)NT * DD;            // 0.256M
    if (i < NEL) {
        float4 v = *(const float4*)(entf + i);
        *(bf16x4*)(entb + i) = bf16x4{f2b(v.x), f2b(v.y), f2b(v.z), f2b(v.w)};
    } else if (i < NEL + NTL) {
        long j = i - NEL;
        float4 v = *(const float4*)(topf + j);
        *(bf16x4*)(topb + j) = bf16x4{f2b(v.x), f2b(v.y), f2b(v.z), f2b(v.w)};
    } else {
        long j = i - NEL - NTL;                // 0 .. 12.8M
        long row = j >> 7, col = j & 127;      // news [NN x 128], 4-aligned col
        float4 v = *(const float4*)(news + j);
        *(bf16x4*)(X + row * K1 + col) = bf16x4{f2b(v.x), f2b(v.y), f2b(v.z), f2b(v.w)};
    }
}

// ---- partition edges into fixed-capacity buckets (no pre-hist, no scan) ----
// bucket b region = [b*ECAP, b*ECAP + cnt_b); reservation via global atomicAdd.
__global__ __launch_bounds__(256) void scatter_bucket(const int* __restrict__ er,
                                                      const int* __restrict__ ec,
                                                      const int* __restrict__ tr,
                                                      const int* __restrict__ tc,
                                                      int* __restrict__ cnt_e,
                                                      int* __restrict__ cnt_t,
                                                      int* __restrict__ be,
                                                      int* __restrict__ bt) {
    __shared__ int lhe[NBKT], lht[NBKT];   // counts, then local cursors
    __shared__ int lbe[NBKT], lbt[NBKT];   // reserved global bases
    const int tid = threadIdx.x;
    for (int i = tid; i < NBKT; i += 256) { lhe[i] = 0; lht[i] = 0; }
    __syncthreads();
    const int base = blockIdx.x * 4096;
    #pragma unroll 4
    for (int k = 0; k < 16; k++) {
        int e = base + k * 256 + tid;
        if (e < NEDGE) {
            atomicAdd(&lhe[er[e] >> 8], 1);
            atomicAdd(&lht[tr[e] >> 8], 1);
        }
    }
    __syncthreads();
    for (int i = tid; i < NBKT; i += 256) {
        int c = lhe[i];
        lbe[i] = c ? (i * ECAP + atomicAdd(&cnt_e[i], c)) : 0;
        lhe[i] = 0;
        c = lht[i];
        lbt[i] = c ? (i * ECAP + atomicAdd(&cnt_t[i], c)) : 0;
        lht[i] = 0;
    }
    __syncthreads();
    #pragma unroll 4
    for (int k = 0; k < 16; k++) {
        int e = base + k * 256 + tid;
        if (e < NEDGE) {
            int r = er[e];
            int b = r >> 8;
            int p = lbe[b] + atomicAdd(&lhe[b], 1);
            be[p] = ((r & 255) << 16) | ec[e];
            r = tr[e];
            b = r >> 8;
            p = lbt[b] + atomicAdd(&lht[b], 1);
            bt[p] = ((r & 255) << 16) | tc[e];
        }
    }
}

// ---- per-bucket exact CSR: local hist + scan -> per-node [starts,ends) + cols ----
__global__ __launch_bounds__(256) void bucket_csr(const int* __restrict__ be,
                                                  const int* __restrict__ bt,
                                                  const int* __restrict__ cnt_e,
                                                  const int* __restrict__ cnt_t,
                                                  int* __restrict__ starts_e,
                                                  int* __restrict__ ends_e,
                                                  int* __restrict__ starts_t,
                                                  int* __restrict__ ends_t,
                                                  int* __restrict__ se,
                                                  int* __restrict__ st) {
    const int* buf  = blockIdx.y ? bt : be;
    const int* bcnt = blockIdx.y ? cnt_t : cnt_e;
    int* starts     = blockIdx.y ? starts_t : starts_e;
    int* ends       = blockIdx.y ? ends_t : ends_e;
    int* sout       = blockIdx.y ? st : se;
    const int b = blockIdx.x;
    const int tid = threadIdx.x;
    const int start = b * ECAP;
    int cnt = bcnt[b]; if (cnt > ECAP) cnt = ECAP;   // safety clamp

    __shared__ int scn[256];
    __shared__ int lcur[256];
    scn[tid] = 0;
    __syncthreads();
    for (int i = tid; i < cnt; i += 256)
        atomicAdd(&scn[buf[start + i] >> 16], 1);
    __syncthreads();
    #pragma unroll
    for (int off = 1; off < 256; off <<= 1) {
        int v = (tid >= off) ? scn[tid - off] : 0;
        __syncthreads();
        scn[tid] += v;
        __syncthreads();
    }
    const int node = b * 256 + tid;
    const int excl = start + (tid ? scn[tid - 1] : 0);
    if (node < NN) {
        starts[node] = excl;
        ends[node]   = start + scn[tid];
    }
    lcur[tid] = excl;
    __syncthreads();
    for (int i = tid; i < cnt; i += 256) {
        int v = buf[start + i];
        int p = atomicAdd(&lcur[v >> 16], 1);
        sout[p] = v & 0xFFFF;
    }
}

// ---- gather-aggregate (bf16 tables) -> X cols 128..383 ----
__global__ __launch_bounds__(256) void aggregate2(const __bf16* __restrict__ entb,
                                                  const __bf16* __restrict__ topb,
                                                  const int* __restrict__ starts_e,
                                                  const int* __restrict__ ends_e,
                                                  const int* __restrict__ starts_t,
                                                  const int* __restrict__ ends_t,
                                                  const int* __restrict__ se,
                                                  const int* __restrict__ st,
                                                  __bf16* __restrict__ X) {
    const int wave = threadIdx.x >> 6, lane = threadIdx.x & 63;
    const int node = blockIdx.x * 4 + wave;
    if (node >= NN) return;
    const int h = lane >> 4;        // 0..3: edge phase
    const int d = (lane & 15) * 8;  // dim group of 8

    float ea[8] = {0,0,0,0,0,0,0,0};
    float pa[8] = {0,0,0,0,0,0,0,0};

    const int s0 = starts_e[node], s1 = ends_e[node];
    int i = s0 + h;
    for (; i + 12 < s1; i += 16) {
        int c0 = se[i], c1 = se[i + 4], c2 = se[i + 8], c3 = se[i + 12];
        bf16x8 v0 = *(const bf16x8*)(entb + (long)c0 * DD + d);
        bf16x8 v1 = *(const bf16x8*)(entb + (long)c1 * DD + d);
        bf16x8 v2 = *(const bf16x8*)(entb + (long)c2 * DD + d);
        bf16x8 v3 = *(const bf16x8*)(entb + (long)c3 * DD + d);
        #pragma unroll
        for (int j = 0; j < 8; j++)
            ea[j] += ((float)v0[j] + (float)v1[j]) + ((float)v2[j] + (float)v3[j]);
    }
    for (; i < s1; i += 4) {
        bf16x8 v = *(const bf16x8*)(entb + (long)se[i] * DD + d);
        #pragma unroll
        for (int j = 0; j < 8; j++) ea[j] += (float)v[j];
    }

    const int t0 = starts_t[node], t1 = ends_t[node];
    i = t0 + h;
    for (; i + 12 < t1; i += 16) {
        int c0 = st[i], c1 = st[i + 4], c2 = st[i + 8], c3 = st[i + 12];
        bf16x8 v0 = *(const bf16x8*)(topb + (long)c0 * DD + d);
        bf16x8 v1 = *(const bf16x8*)(topb + (long)c1 * DD + d);
        bf16x8 v2 = *(const bf16x8*)(topb + (long)c2 * DD + d);
        bf16x8 v3 = *(const bf16x8*)(topb + (long)c3 * DD + d);
        #pragma unroll
        for (int j = 0; j < 8; j++)
            pa[j] += ((float)v0[j] + (float)v1[j]) + ((float)v2[j] + (float)v3[j]);
    }
    for (; i < t1; i += 4) {
        bf16x8 v = *(const bf16x8*)(topb + (long)st[i] * DD + d);
        #pragma unroll
        for (int j = 0; j < 8; j++) pa[j] += (float)v[j];
    }

    #pragma unroll
    for (int j = 0; j < 8; j++) {
        ea[j] += __shfl_xor(ea[j], 16, 64);
        ea[j] += __shfl_xor(ea[j], 32, 64);
        pa[j] += __shfl_xor(pa[j], 16, 64);
        pa[j] += __shfl_xor(pa[j], 32, 64);
    }

    const float ie = 1.0f / ((float)(s1 - s0) + 1e-8f);
    const float it = 1.0f / ((float)(t1 - t0) + 1e-8f);
    __bf16* xr = X + (long)node * K1;
    if (h == 1) {
        *(bf16x8*)(xr + DD + d) = bf16x8{f2b(ea[0]*ie), f2b(ea[1]*ie), f2b(ea[2]*ie), f2b(ea[3]*ie),
                                         f2b(ea[4]*ie), f2b(ea[5]*ie), f2b(ea[6]*ie), f2b(ea[7]*ie)};
    } else if (h == 2) {
        *(bf16x8*)(xr + 2*DD + d) = bf16x8{f2b(pa[0]*it), f2b(pa[1]*it), f2b(pa[2]*it), f2b(pa[3]*it),
                                           f2b(pa[4]*it), f2b(pa[5]*it), f2b(pa[6]*it), f2b(pa[7]*it)};
    }
}

// ---- W1 [384,512] -> W1T bf16 [512,384]; W2 [512,128] -> W2T bf16 [128,512] ----
__global__ void conv_w(const float* __restrict__ W1, const float* __restrict__ W2,
                       __bf16* __restrict__ W1T, __bf16* __restrict__ W2T) {
    int i = blockIdx.x * 256 + threadIdx.x;
    if (i < K1 * HID) {
        int k = i / HID, n = i % HID;
        W1T[n * K1 + k] = f2b(W1[i]);
    } else {
        int j = i - K1 * HID;
        if (j < HID * OUTD) {
            int k = j / OUTD, n = j % OUTD;
            W2T[n * HID + k] = f2b(W2[j]);
        }
    }
}

// ======== fused MLP: out = (tanh(X@W1T^T + b1)) @ W2T^T + b2 ========
// R4-measured-best structure (155 us): kt loop = 3-buffer depth-2 prefetch with
// COUNTED vmcnt + raw s_barrier; kk loop = 2-buffer __syncthreads rhythm.

// stage a [128 x 32] bf16 tile (swizzled); exactly 2 gll16 per thread
__device__ __forceinline__ void stage_tile(const __bf16* __restrict__ src, int ldK,
                                           int k0, int row0, int rowmax,
                                           __bf16* lds, int w, int lane) {
    #pragma unroll
    for (int half = 0; half < 2; half++) {
        int ss = w * 64 + half * 256 + lane;
        int r = ss >> 2;
        int sw = (r & 3) ^ ((r >> 2) & 3);
        int c = (ss & 3) ^ sw;
        int gr = row0 + r; if (gr >= rowmax) gr = rowmax - 1;
        gll16(src + (long)gr * ldK + k0 + c * 8,
              lds + (w * 64 + half * 256) * 8);
    }
}

// read fragment (logical row r, k-chunk q) from swizzled [128 x 32] tile
__device__ __forceinline__ bf16x8 frag(const __bf16* lds, int r, int q) {
    int sw = (r & 3) ^ ((r >> 2) & 3);
    return *(const bf16x8*)(lds + (r * 4 + (q ^ sw)) * 8);
}

// Hs [128 rows x 128 k] swizzled: chunk16 = kk*4+quad
__device__ __forceinline__ void hs_write(__bf16* Hs, int r, int c, __bf16 v) {
    int ch = c >> 3;
    int pch = ((((ch >> 2) ^ ((r >> 2) & 3)) << 2) | ((ch & 3) ^ (r & 3)));
    Hs[(r * 16 + pch) * 8 + (c & 7)] = v;
}
__device__ __forceinline__ bf16x8 hs_frag(const __bf16* Hs, int r, int kk, int q) {
    int pch = (((kk ^ ((r >> 2) & 3)) << 2) | (q ^ (r & 3)));
    return *(const bf16x8*)(Hs + (r * 16 + pch) * 8);
}

__global__ __launch_bounds__(256, 2) void mlp_fused(const __bf16* __restrict__ X,
                                                    const __bf16* __restrict__ W1T,
                                                    const float* __restrict__ b1,
                                                    const __bf16* __restrict__ W2T,
                                                    const float* __restrict__ b2,
                                                    float* __restrict__ out) {
    __shared__ __bf16 Xs[3][128 * 32];  // 3 x 8 KB
    __shared__ __bf16 Ws[3][128 * 32];  // 3 x 8 KB
    __shared__ __bf16 Hs[128 * 128];    // 32 KB  (total 80 KB -> 2 blocks/CU)
    const int bm = blockIdx.x * 128;
    const int t = threadIdx.x;
    const int lane = t & 63;
    const int w = t >> 6;
    const int quad = lane >> 4;
    const int l16 = lane & 15;
    const int wm = w >> 1, wn = w & 1;

    f32x4 oacc[4][4];
    #pragma unroll
    for (int i = 0; i < 4; i++)
        #pragma unroll
        for (int j = 0; j < 4; j++)
            #pragma unroll
            for (int r = 0; r < 4; r++) oacc[i][j][r] = 0.0f;

    // prologue: issue groups g0 (kt0) and g1 (kt1) for nc=0
    stage_tile(X,   K1, 0,  bm, NN,  Xs[0], w, lane);
    stage_tile(W1T, K1, 0,  0,  HID, Ws[0], w, lane);
    stage_tile(X,   K1, 32, bm, NN,  Xs[1], w, lane);
    stage_tile(W1T, K1, 32, 0,  HID, Ws[1], w, lane);

    for (int nc = 0; nc < 4; nc++) {
        f32x4 hacc[4][4];
        #pragma unroll
        for (int i = 0; i < 4; i++)
            #pragma unroll
            for (int j = 0; j < 4; j++)
                #pragma unroll
                for (int r = 0; r < 4; r++) hacc[i][j][r] = 0.0f;

        // ---- kt loop: counted-vmcnt 3-buffer pipeline ----
        #pragma unroll
        for (int kt = 0; kt < 12; kt++) {
            const int cb = kt % 3;
            // wait for this buffer's loads (issued at kt-2); keep newer group flying
            if (kt < 11) asm volatile("s_waitcnt vmcnt(4)" ::: "memory");
            else         asm volatile("s_waitcnt vmcnt(0)" ::: "memory");
            __builtin_amdgcn_s_barrier();
            bf16x8 af[4], bfr[4];
            #pragma unroll
            for (int i = 0; i < 4; i++) {
                af[i]  = frag(Xs[cb], wm * 64 + i * 16 + l16, quad);
                bfr[i] = frag(Ws[cb], wn * 64 + i * 16 + l16, quad);
            }
            if (kt < 10) {
                // stage kt+2 into buffer (kt+2)%3 (last read at kt-1; barrier-safe)
                const int nb = (kt + 2) % 3;
                stage_tile(X,   K1, (kt + 2) * 32, bm,       NN,  Xs[nb], w, lane);
                stage_tile(W1T, K1, (kt + 2) * 32, nc * 128, HID, Ws[nb], w, lane);
            }
            __builtin_amdgcn_s_setprio(1);
            #pragma unroll
            for (int i = 0; i < 4; i++)
                #pragma unroll
                for (int j = 0; j < 4; j++)
                    hacc[i][j] = __builtin_amdgcn_mfma_f32_16x16x32_bf16(af[i], bfr[j], hacc[i][j], 0, 0, 0);
            __builtin_amdgcn_s_setprio(0);
        }
        __syncthreads();   // all waves done reading Xs[2]/Ws[2]

        // stage W2 kk0 tile into Ws[2]; flies during the tanh pass
        stage_tile(W2T, HID, nc * 128, 0, OUTD, Ws[2], w, lane);

        // bias + tanh -> Hs (C/D layout: row=quad*4+reg, col=l16)
        #pragma unroll
        for (int j = 0; j < 4; j++) {
            const int col = wn * 64 + j * 16 + l16;
            const float bb = b1[nc * 128 + col];
            #pragma unroll
            for (int i = 0; i < 4; i++) {
                const int rbase = wm * 64 + i * 16 + quad * 4;
                #pragma unroll
                for (int r = 0; r < 4; r++)
                    hs_write(Hs, rbase + r, col, f2b(ftanh(hacc[i][j][r] + bb)));
            }
        }
        __syncthreads();   // Hs visible; W2 kk0 drained

        // ---- O += H_chunk @ W2T[:, nc*128..+128]^T ----
        for (int kk = 0; kk < 4; kk++) {
            __bf16* curb = (kk & 1) ? Xs[2] : Ws[2];
            __bf16* nxtb = (kk & 1) ? Ws[2] : Xs[2];
            if (kk < 3)
                stage_tile(W2T, HID, nc * 128 + (kk + 1) * 32, 0, OUTD, nxtb, w, lane);
            if (nc < 3) {
                if (kk == 2) {
                    stage_tile(X,   K1, 0, bm,             NN,  Xs[0], w, lane);
                    stage_tile(W1T, K1, 0, (nc + 1) * 128, HID, Ws[0], w, lane);
                } else if (kk == 3) {
                    stage_tile(X,   K1, 32, bm,             NN,  Xs[1], w, lane);
                    stage_tile(W1T, K1, 32, (nc + 1) * 128, HID, Ws[1], w, lane);
                }
            }
            bf16x8 af[4], bfr[4];
            #pragma unroll
            for (int i = 0; i < 4; i++) {
                af[i]  = hs_frag(Hs, wm * 64 + i * 16 + l16, kk, quad);
                bfr[i] = frag(curb, wn * 64 + i * 16 + l16, quad);
            }
            __builtin_amdgcn_s_setprio(1);
            #pragma unroll
            for (int i = 0; i < 4; i++)
                #pragma unroll
                for (int j = 0; j < 4; j++)
                    oacc[i][j] = __builtin_amdgcn_mfma_f32_16x16x32_bf16(af[i], bfr[j], oacc[i][j], 0, 0, 0);
            __builtin_amdgcn_s_setprio(0);
            __syncthreads();   // drains staged loads; separates buffer reuse
        }
    }

    // epilogue: out f32 [NN x 128]; j innermost -> full-line coverage fast
    float bb[4];
    #pragma unroll
    for (int j = 0; j < 4; j++) bb[j] = b2[wn * 64 + j * 16 + l16];
    #pragma unroll
    for (int i = 0; i < 4; i++) {
        #pragma unroll
        for (int r = 0; r < 4; r++) {
            const int gr = bm + wm * 64 + i * 16 + quad * 4 + r;
            if (gr < NN) {
                float* orow = out + (long)gr * OUTD + wn * 64 + l16;
                #pragma unroll
                for (int j = 0; j < 4; j++)
                    orow[j * 16] = oacc[i][j][r] + bb[j];
            }
        }
    }
}

extern "C" void kernel_launch(void* const* d_in, const int* in_sizes, int n_in,
                              void* d_out, int out_size, void* d_ws, size_t ws_size,
                              hipStream_t stream) {
    const float* news  = (const float*)d_in[0];
    const float* ent_f = (const float*)d_in[1];
    const float* top_f = (const float*)d_in[2];
    const int* ent_row = (const int*)d_in[3];
    const int* ent_col = (const int*)d_in[4];
    const int* top_row = (const int*)d_in[5];
    const int* top_col = (const int*)d_in[6];
    const float* W1 = (const float*)d_in[7];
    const float* b1 = (const float*)d_in[8];
    const float* W2 = (const float*)d_in[9];
    const float* b2 = (const float*)d_in[10];

    char* ws = (char*)d_ws;
    //   [0,        400000)    starts_e int[100000]
    //   [400016,   800016)    ends_e   int[100000]
    //   [800032,  1200032)    starts_t int[100000]
    //   [1200048, 1600048)    ends_t   int[100000]
    //   [1600064, 1601628)    cnt_e    int[391]
    //   [1601664, 1603228)    cnt_t    int[391]
    //   [26406336, 39206336)  entb bf16 [50000*128]
    //   [39206336, 39718336)  topb bf16 [2000*128]
    //   [40000000, 47206912)  be packed int[391*4608]
    //   [48000000, 55206912)  bt packed int[391*4608]
    //   [56000000, 63206912)  se int[391*4608]
    //   [64000000, 71206912)  st int[391*4608]
    //   [102400000,179200000) X bf16 [100000*384]
    //   [179200000,179593216) W1T bf16 [512*384]
    //   [179593216,179724288) W2T bf16 [128*512]
    int* starts_e = (int*)(ws + 0);
    int* ends_e   = (int*)(ws + 400016);
    int* starts_t = (int*)(ws + 800032);
    int* ends_t   = (int*)(ws + 1200048);
    int* cnt_e    = (int*)(ws + 1600064);
    int* cnt_t    = (int*)(ws + 1601664);
    __bf16* entb = (__bf16*)(ws + 26406336);
    __bf16* topb = (__bf16*)(ws + 39206336);
    int* be      = (int*)(ws + 40000000);
    int* bt      = (int*)(ws + 48000000);
    int* se      = (int*)(ws + 56000000);
    int* st      = (int*)(ws + 64000000);
    __bf16* X   = (__bf16*)(ws + 102400000);
    __bf16* W1T = (__bf16*)(ws + 179200000);
    __bf16* W2T = (__bf16*)(ws + 179593216);

    hipMemsetAsync(ws + 1600064, 0, 3200, stream);   // zero cnt_e/cnt_t
    conv_w<<<1024, 256, 0, stream>>>(W1, W2, W1T, W2T);
    conv_feats<<<19000, 256, 0, stream>>>(ent_f, top_f, news, entb, topb, X);
    scatter_bucket<<<392, 256, 0, stream>>>(ent_row, ent_col, top_row, top_col,
                                            cnt_e, cnt_t, be, bt);
    bucket_csr<<<dim3(NBKT, 2), 256, 0, stream>>>(be, bt, cnt_e, cnt_t,
                                                  starts_e, ends_e, starts_t, ends_t,
                                                  se, st);
    aggregate2<<<NN / 4, 256, 0, stream>>>(entb, topb, starts_e, ends_e,
                                           starts_t, ends_t, se, st, X);
    mlp_fused<<<782, 256, 0, stream>>>(X, W1T, b1, W2T, b2, (float*)d_out);
}

// Round 15
// 488.860 us; speedup vs baseline: 1.1011x; 1.0090x over previous
//
#include <hip/hip_runtime.h>
#include <hip/hip_bf16.h>

#define NN 100000
#define NE 50000
#define NT 2000
#define DD 128
#define NEDGE 1600000
#define HID 512
#define OUTD 128
#define K1 (3*DD)   // 384: X layout [news | ent_agg | top_agg]
#define NBKT 391    // ceil(100000/256) buckets of 256 nodes
#define ECAP 4608   // fixed bucket capacity: mean 4096 + 8 sigma

typedef __bf16 bf16x8 __attribute__((ext_vector_type(8)));
typedef __bf16 bf16x4 __attribute__((ext_vector_type(4)));
typedef float  f32x4  __attribute__((ext_vector_type(4)));

__device__ __forceinline__ __bf16 f2b(float f) {
    __hip_bfloat16 h = __float2bfloat16(f);
    union { __hip_bfloat16 h; __bf16 b; } u; u.h = h; return u.b;
}

__device__ __forceinline__ void gll16(const void* g, void* l) {
    __builtin_amdgcn_global_load_lds((const __attribute__((address_space(1))) void*)g,
                                     (__attribute__((address_space(3))) void*)l, 16, 0, 0);
}

__device__ __forceinline__ float ftanh(float x) {
    x = fminf(fmaxf(x, -15.f), 15.f);
    float t = __expf(2.f * x);
    return (t - 1.f) / (t + 1.f);
}

// ---- convert: ent/top tables -> bf16 tables; news -> bf16 into X cols 0..127 ----
__global__ void conv_feats(const float* __restrict__ entf, const float* __restrict__ topf,
                           const float* __restrict__ news,
                           __bf16* __restrict__ entb, __bf16* __restrict__ topb,
                           __bf16* __restrict__ X) {
    long i = ((long)blockIdx.x * 256 + threadIdx.x) * 4;
    const long NEL = (long)NE * DD;            // 6.4M
    const long NTL = (long)NT * DD;            // 0.256M
    if (i < NEL) {
        float4 v = *(const float4*)(entf + i);
        *(bf16x4*)(entb + i) = bf16x4{f2b(v.x), f2b(v.y), f2b(v.z), f2b(v.w)};
    } else if (i < NEL + NTL) {
        long j = i - NEL;
        float4 v = *(const float4*)(topf + j);
        *(bf16x4*)(topb + j) = bf16x4{f2b(v.x), f2b(v.y), f2b(v.z), f2b(v.w)};
    } else {
        long j = i - NEL - NTL;                // 0 .. 12.8M
        long row = j >> 7, col = j & 127;      // news [NN x 128], 4-aligned col
        float4 v = *(const float4*)(news + j);
        *(bf16x4*)(X + row * K1 + col) = bf16x4{f2b(v.x), f2b(v.y), f2b(v.z), f2b(v.w)};
    }
}

// ---- partition edges into fixed-capacity buckets (no pre-hist, no scan) ----
// bucket b region = [b*ECAP, b*ECAP + cnt_b); reservation via global atomicAdd.
__global__ __launch_bounds__(256) void scatter_bucket(const int* __restrict__ er,
                                                      const int* __restrict__ ec,
                                                      const int* __restrict__ tr,
                                                      const int* __restrict__ tc,
                                                      int* __restrict__ cnt_e,
                                                      int* __restrict__ cnt_t,
                                                      int* __restrict__ be,
                                                      int* __restrict__ bt) {
    __shared__ int lhe[NBKT], lht[NBKT];   // counts, then local cursors
    __shared__ int lbe[NBKT], lbt[NBKT];   // reserved global bases
    const int tid = threadIdx.x;
    for (int i = tid; i < NBKT; i += 256) { lhe[i] = 0; lht[i] = 0; }
    __syncthreads();
    const int base = blockIdx.x * 4096;
    #pragma unroll 4
    for (int k = 0; k < 16; k++) {
        int e = base + k * 256 + tid;
        if (e < NEDGE) {
            atomicAdd(&lhe[er[e] >> 8], 1);
            atomicAdd(&lht[tr[e] >> 8], 1);
        }
    }
    __syncthreads();
    for (int i = tid; i < NBKT; i += 256) {
        int c = lhe[i];
        lbe[i] = c ? (i * ECAP + atomicAdd(&cnt_e[i], c)) : 0;
        lhe[i] = 0;
        c = lht[i];
        lbt[i] = c ? (i * ECAP + atomicAdd(&cnt_t[i], c)) : 0;
        lht[i] = 0;
    }
    __syncthreads();
    #pragma unroll 4
    for (int k = 0; k < 16; k++) {
        int e = base + k * 256 + tid;
        if (e < NEDGE) {
            int r = er[e];
            int b = r >> 8;
            int p = lbe[b] + atomicAdd(&lhe[b], 1);
            be[p] = ((r & 255) << 16) | ec[e];
            r = tr[e];
            b = r >> 8;
            p = lbt[b] + atomicAdd(&lht[b], 1);
            bt[p] = ((r & 255) << 16) | tc[e];
        }
    }
}

// ---- per-bucket exact CSR: local hist + scan -> per-node [starts,ends) + cols ----
__global__ __launch_bounds__(256) void bucket_csr(const int* __restrict__ be,
                                                  const int* __restrict__ bt,
                                                  const int* __restrict__ cnt_e,
                                                  const int* __restrict__ cnt_t,
                                                  int* __restrict__ starts_e,
                                                  int* __restrict__ ends_e,
                                                  int* __restrict__ starts_t,
                                                  int* __restrict__ ends_t,
                                                  int* __restrict__ se,
                                                  int* __restrict__ st) {
    const int* buf  = blockIdx.y ? bt : be;
    const int* bcnt = blockIdx.y ? cnt_t : cnt_e;
    int* starts     = blockIdx.y ? starts_t : starts_e;
    int* ends       = blockIdx.y ? ends_t : ends_e;
    int* sout       = blockIdx.y ? st : se;
    const int b = blockIdx.x;
    const int tid = threadIdx.x;
    const int start = b * ECAP;
    int cnt = bcnt[b]; if (cnt > ECAP) cnt = ECAP;   // safety clamp

    __shared__ int scn[256];
    __shared__ int lcur[256];
    scn[tid] = 0;
    __syncthreads();
    for (int i = tid; i < cnt; i += 256)
        atomicAdd(&scn[buf[start + i] >> 16], 1);
    __syncthreads();
    #pragma unroll
    for (int off = 1; off < 256; off <<= 1) {
        int v = (tid >= off) ? scn[tid - off] : 0;
        __syncthreads();
        scn[tid] += v;
        __syncthreads();
    }
    const int node = b * 256 + tid;
    const int excl = start + (tid ? scn[tid - 1] : 0);
    if (node < NN) {
        starts[node] = excl;
        ends[node]   = start + scn[tid];
    }
    lcur[tid] = excl;
    __syncthreads();
    for (int i = tid; i < cnt; i += 256) {
        int v = buf[start + i];
        int p = atomicAdd(&lcur[v >> 16], 1);
        sout[p] = v & 0xFFFF;
    }
}

// ---- gather-aggregate (bf16 tables) -> X cols 128..383 ----
// One wave per node. ONE coalesced index load per stream staged to a per-wave
// LDS slab; inner loop reads indices via ds_read (quarter-uniform broadcast,
// no cross-lane register ops, no barrier: same-wave LDS RAW is hw-ordered).
__global__ __launch_bounds__(256) void aggregate2(const __bf16* __restrict__ entb,
                                                  const __bf16* __restrict__ topb,
                                                  const int* __restrict__ starts_e,
                                                  const int* __restrict__ ends_e,
                                                  const int* __restrict__ starts_t,
                                                  const int* __restrict__ ends_t,
                                                  const int* __restrict__ se,
                                                  const int* __restrict__ st,
                                                  __bf16* __restrict__ X) {
    __shared__ int sidx[4][128];   // [wave][0..63 ent, 64..127 top]
    const int wave = threadIdx.x >> 6, lane = threadIdx.x & 63;
    const int node = blockIdx.x * 4 + wave;
    if (node >= NN) return;
    const int g = lane >> 4;        // 0..3: edge slot
    const int d = (lane & 15) * 8;  // dim group of 8

    const int s0 = starts_e[node], s1 = ends_e[node];
    const int t0 = starts_t[node], t1 = ends_t[node];
    const int dege = s1 - s0, degt = t1 - t0;
    const int lim_e = dege < 64 ? dege : 64;
    const int lim_t = degt < 64 ? degt : 64;

    int* my = sidx[wave];
    if (lane < lim_e) my[lane] = se[s0 + lane];
    if (lane < lim_t) my[64 + lane] = st[t0 + lane];

    float ea[8] = {0,0,0,0,0,0,0,0};
    float pa[8] = {0,0,0,0,0,0,0,0};

    const int lim = lim_e > lim_t ? lim_e : lim_t;
    for (int e = g; e < lim; e += 4) {
        if (e < lim_e) {
            bf16x8 v = *(const bf16x8*)(entb + (long)my[e] * DD + d);
            #pragma unroll
            for (int j = 0; j < 8; j++) ea[j] += (float)v[j];
        }
        if (e < lim_t) {
            bf16x8 v = *(const bf16x8*)(topb + (long)my[64 + e] * DD + d);
            #pragma unroll
            for (int j = 0; j < 8; j++) pa[j] += (float)v[j];
        }
    }
    // cold tails (deg>64: P ~ 1e-7 for Binomial(1.6M, 1e-5) mean 16)
    for (int e = 64 + g; e < dege; e += 4) {
        bf16x8 v = *(const bf16x8*)(entb + (long)se[s0 + e] * DD + d);
        #pragma unroll
        for (int j = 0; j < 8; j++) ea[j] += (float)v[j];
    }
    for (int e = 64 + g; e < degt; e += 4) {
        bf16x8 v = *(const bf16x8*)(topb + (long)st[t0 + e] * DD + d);
        #pragma unroll
        for (int j = 0; j < 8; j++) pa[j] += (float)v[j];
    }

    #pragma unroll
    for (int j = 0; j < 8; j++) {
        ea[j] += __shfl_xor(ea[j], 16, 64);
        ea[j] += __shfl_xor(ea[j], 32, 64);
        pa[j] += __shfl_xor(pa[j], 16, 64);
        pa[j] += __shfl_xor(pa[j], 32, 64);
    }

    const float ie = 1.0f / ((float)dege + 1e-8f);
    const float it = 1.0f / ((float)degt + 1e-8f);
    __bf16* xr = X + (long)node * K1;
    if (g == 1) {
        *(bf16x8*)(xr + DD + d) = bf16x8{f2b(ea[0]*ie), f2b(ea[1]*ie), f2b(ea[2]*ie), f2b(ea[3]*ie),
                                         f2b(ea[4]*ie), f2b(ea[5]*ie), f2b(ea[6]*ie), f2b(ea[7]*ie)};
    } else if (g == 2) {
        *(bf16x8*)(xr + 2*DD + d) = bf16x8{f2b(pa[0]*it), f2b(pa[1]*it), f2b(pa[2]*it), f2b(pa[3]*it),
                                           f2b(pa[4]*it), f2b(pa[5]*it), f2b(pa[6]*it), f2b(pa[7]*it)};
    }
}

// ---- W1 [384,512] -> W1T bf16 [512,384]; W2 [512,128] -> W2T bf16 [128,512] ----
__global__ void conv_w(const float* __restrict__ W1, const float* __restrict__ W2,
                       __bf16* __restrict__ W1T, __bf16* __restrict__ W2T) {
    int i = blockIdx.x * 256 + threadIdx.x;
    if (i < K1 * HID) {
        int k = i / HID, n = i % HID;
        W1T[n * K1 + k] = f2b(W1[i]);
    } else {
        int j = i - K1 * HID;
        if (j < HID * OUTD) {
            int k = j / OUTD, n = j % OUTD;
            W2T[n * HID + k] = f2b(W2[j]);
        }
    }
}

// ======== fused MLP: out = (tanh(X@W1T^T + b1)) @ W2T^T + b2 ========
// R4-measured-best structure: kt loop = 3-buffer depth-2 prefetch with
// COUNTED vmcnt + raw s_barrier; kk loop = 2-buffer __syncthreads rhythm.

// stage a [128 x 32] bf16 tile (swizzled); exactly 2 gll16 per thread
__device__ __forceinline__ void stage_tile(const __bf16* __restrict__ src, int ldK,
                                           int k0, int row0, int rowmax,
                                           __bf16* lds, int w, int lane) {
    #pragma unroll
    for (int half = 0; half < 2; half++) {
        int ss = w * 64 + half * 256 + lane;
        int r = ss >> 2;
        int sw = (r & 3) ^ ((r >> 2) & 3);
        int c = (ss & 3) ^ sw;
        int gr = row0 + r; if (gr >= rowmax) gr = rowmax - 1;
        gll16(src + (long)gr * ldK + k0 + c * 8,
              lds + (w * 64 + half * 256) * 8);
    }
}

// read fragment (logical row r, k-chunk q) from swizzled [128 x 32] tile
__device__ __forceinline__ bf16x8 frag(const __bf16* lds, int r, int q) {
    int sw = (r & 3) ^ ((r >> 2) & 3);
    return *(const bf16x8*)(lds + (r * 4 + (q ^ sw)) * 8);
}

// Hs [128 rows x 128 k] swizzled: chunk16 = kk*4+quad
__device__ __forceinline__ void hs_write(__bf16* Hs, int r, int c, __bf16 v) {
    int ch = c >> 3;
    int pch = ((((ch >> 2) ^ ((r >> 2) & 3)) << 2) | ((ch & 3) ^ (r & 3)));
    Hs[(r * 16 + pch) * 8 + (c & 7)] = v;
}
__device__ __forceinline__ bf16x8 hs_frag(const __bf16* Hs, int r, int kk, int q) {
    int pch = (((kk ^ ((r >> 2) & 3)) << 2) | (q ^ (r & 3)));
    return *(const bf16x8*)(Hs + (r * 16 + pch) * 8);
}

__global__ __launch_bounds__(256, 2) void mlp_fused(const __bf16* __restrict__ X,
                                                    const __bf16* __restrict__ W1T,
                                                    const float* __restrict__ b1,
                                                    const __bf16* __restrict__ W2T,
                                                    const float* __restrict__ b2,
                                                    float* __restrict__ out) {
    __shared__ __bf16 Xs[3][128 * 32];  // 3 x 8 KB
    __shared__ __bf16 Ws[3][128 * 32];  // 3 x 8 KB
    __shared__ __bf16 Hs[128 * 128];    // 32 KB  (total 80 KB -> 2 blocks/CU)
    const int bm = blockIdx.x * 128;
    const int t = threadIdx.x;
    const int lane = t & 63;
    const int w = t >> 6;
    const int quad = lane >> 4;
    const int l16 = lane & 15;
    const int wm = w >> 1, wn = w & 1;

    f32x4 oacc[4][4];
    #pragma unroll
    for (int i = 0; i < 4; i++)
        #pragma unroll
        for (int j = 0; j < 4; j++)
            #pragma unroll
            for (int r = 0; r < 4; r++) oacc[i][j][r] = 0.0f;

    // prologue: issue groups g0 (kt0) and g1 (kt1) for nc=0
    stage_tile(X,   K1, 0,  bm, NN,  Xs[0], w, lane);
    stage_tile(W1T, K1, 0,  0,  HID, Ws[0], w, lane);
    stage_tile(X,   K1, 32, bm, NN,  Xs[1], w, lane);
    stage_tile(W1T, K1, 32, 0,  HID, Ws[1], w, lane);

    for (int nc = 0; nc < 4; nc++) {
        f32x4 hacc[4][4];
        #pragma unroll
        for (int i = 0; i < 4; i++)
            #pragma unroll
            for (int j = 0; j < 4; j++)
                #pragma unroll
                for (int r = 0; r < 4; r++) hacc[i][j][r] = 0.0f;

        // ---- kt loop: counted-vmcnt 3-buffer pipeline ----
        #pragma unroll
        for (int kt = 0; kt < 12; kt++) {
            const int cb = kt % 3;
            // wait for this buffer's loads (issued at kt-2); keep newer group flying
            if (kt < 11) asm volatile("s_waitcnt vmcnt(4)" ::: "memory");
            else         asm volatile("s_waitcnt vmcnt(0)" ::: "memory");
            __builtin_amdgcn_s_barrier();
            bf16x8 af[4], bfr[4];
            #pragma unroll
            for (int i = 0; i < 4; i++) {
                af[i]  = frag(Xs[cb], wm * 64 + i * 16 + l16, quad);
                bfr[i] = frag(Ws[cb], wn * 64 + i * 16 + l16, quad);
            }
            if (kt < 10) {
                // stage kt+2 into buffer (kt+2)%3 (last read at kt-1; barrier-safe)
                const int nb = (kt + 2) % 3;
                stage_tile(X,   K1, (kt + 2) * 32, bm,       NN,  Xs[nb], w, lane);
                stage_tile(W1T, K1, (kt + 2) * 32, nc * 128, HID, Ws[nb], w, lane);
            }
            __builtin_amdgcn_s_setprio(1);
            #pragma unroll
            for (int i = 0; i < 4; i++)
                #pragma unroll
                for (int j = 0; j < 4; j++)
                    hacc[i][j] = __builtin_amdgcn_mfma_f32_16x16x32_bf16(af[i], bfr[j], hacc[i][j], 0, 0, 0);
            __builtin_amdgcn_s_setprio(0);
        }
        __syncthreads();   // all waves done reading Xs[2]/Ws[2]

        // stage W2 kk0 tile into Ws[2]; flies during the tanh pass
        stage_tile(W2T, HID, nc * 128, 0, OUTD, Ws[2], w, lane);

        // bias + tanh -> Hs (C/D layout: row=quad*4+reg, col=l16)
        #pragma unroll
        for (int j = 0; j < 4; j++) {
            const int col = wn * 64 + j * 16 + l16;
            const float bb = b1[nc * 128 + col];
            #pragma unroll
            for (int i = 0; i < 4; i++) {
                const int rbase = wm * 64 + i * 16 + quad * 4;
                #pragma unroll
                for (int r = 0; r < 4; r++)
                    hs_write(Hs, rbase + r, col, f2b(ftanh(hacc[i][j][r] + bb)));
            }
        }
        __syncthreads();   // Hs visible; W2 kk0 drained

        // ---- O += H_chunk @ W2T[:, nc*128..+128]^T ----
        for (int kk = 0; kk < 4; kk++) {
            __bf16* curb = (kk & 1) ? Xs[2] : Ws[2];
            __bf16* nxtb = (kk & 1) ? Ws[2] : Xs[2];
            if (kk < 3)
                stage_tile(W2T, HID, nc * 128 + (kk + 1) * 32, 0, OUTD, nxtb, w, lane);
            if (nc < 3) {
                if (kk == 2) {
                    stage_tile(X,   K1, 0, bm,             NN,  Xs[0], w, lane);
                    stage_tile(W1T, K1, 0, (nc + 1) * 128, HID, Ws[0], w, lane);
                } else if (kk == 3) {
                    stage_tile(X,   K1, 32, bm,             NN,  Xs[1], w, lane);
                    stage_tile(W1T, K1, 32, (nc + 1) * 128, HID, Ws[1], w, lane);
                }
            }
            bf16x8 af[4], bfr[4];
            #pragma unroll
            for (int i = 0; i < 4; i++) {
                af[i]  = hs_frag(Hs, wm * 64 + i * 16 + l16, kk, quad);
                bfr[i] = frag(curb, wn * 64 + i * 16 + l16, quad);
            }
            __builtin_amdgcn_s_setprio(1);
            #pragma unroll
            for (int i = 0; i < 4; i++)
                #pragma unroll
                for (int j = 0; j < 4; j++)
                    oacc[i][j] = __builtin_amdgcn_mfma_f32_16x16x32_bf16(af[i], bfr[j], oacc[i][j], 0, 0, 0);
            __builtin_amdgcn_s_setprio(0);
            __syncthreads();   // drains staged loads; separates buffer reuse
        }
    }

    // epilogue: out f32 [NN x 128]; j innermost -> full-line coverage fast
    float bb[4];
    #pragma unroll
    for (int j = 0; j < 4; j++) bb[j] = b2[wn * 64 + j * 16 + l16];
    #pragma unroll
    for (int i = 0; i < 4; i++) {
        #pragma unroll
        for (int r = 0; r < 4; r++) {
            const int gr = bm + wm * 64 + i * 16 + quad * 4 + r;
            if (gr < NN) {
                float* orow = out + (long)gr * OUTD + wn * 64 + l16;
                #pragma unroll
                for (int j = 0; j < 4; j++)
                    orow[j * 16] = oacc[i][j][r] + bb[j];
            }
        }
    }
}

extern "C" void kernel_launch(void* const* d_in, const int* in_sizes, int n_in,
                              void* d_out, int out_size, void* d_ws, size_t ws_size,
                              hipStream_t stream) {
    const float* news  = (const float*)d_in[0];
    const float* ent_f = (const float*)d_in[1];
    const float* top_f = (const float*)d_in[2];
    const int* ent_row = (const int*)d_in[3];
    const int* ent_col = (const int*)d_in[4];
    const int* top_row = (const int*)d_in[5];
    const int* top_col = (const int*)d_in[6];
    const float* W1 = (const float*)d_in[7];
    const float* b1 = (const float*)d_in[8];
    const float* W2 = (const float*)d_in[9];
    const float* b2 = (const float*)d_in[10];

    char* ws = (char*)d_ws;
    //   [0,        400000)    starts_e int[100000]
    //   [400016,   800016)    ends_e   int[100000]
    //   [800032,  1200032)    starts_t int[100000]
    //   [1200048, 1600048)    ends_t   int[100000]
    //   [1600064, 1601628)    cnt_e    int[391]
    //   [1601664, 1603228)    cnt_t    int[391]
    //   [26406336, 39206336)  entb bf16 [50000*128]
    //   [39206336, 39718336)  topb bf16 [2000*128]
    //   [40000000, 47206912)  be packed int[391*4608]
    //   [48000000, 55206912)  bt packed int[391*4608]
    //   [56000000, 63206912)  se int[391*4608]
    //   [64000000, 71206912)  st int[391*4608]
    //   [102400000,179200000) X bf16 [100000*384]
    //   [179200000,179593216) W1T bf16 [512*384]
    //   [179593216,179724288) W2T bf16 [128*512]
    int* starts_e = (int*)(ws + 0);
    int* ends_e   = (int*)(ws + 400016);
    int* starts_t = (int*)(ws + 800032);
    int* ends_t   = (int*)(ws + 1200048);
    int* cnt_e    = (int*)(ws + 1600064);
    int* cnt_t    = (int*)(ws + 1601664);
    __bf16* entb = (__bf16*)(ws + 26406336);
    __bf16* topb = (__bf16*)(ws + 39206336);
    int* be      = (int*)(ws + 40000000);
    int* bt      = (int*)(ws + 48000000);
    int* se      = (int*)(ws + 56000000);
    int* st      = (int*)(ws + 64000000);
    __bf16* X   = (__bf16*)(ws + 102400000);
    __bf16* W1T = (__bf16*)(ws + 179200000);
    __bf16* W2T = (__bf16*)(ws + 179593216);

    hipMemsetAsync(ws + 1600064, 0, 3200, stream);   // zero cnt_e/cnt_t
    conv_w<<<1024, 256, 0, stream>>>(W1, W2, W1T, W2T);
    conv_feats<<<19000, 256, 0, stream>>>(ent_f, top_f, news, entb, topb, X);
    scatter_bucket<<<392, 256, 0, stream>>>(ent_row, ent_col, top_row, top_col,
                                            cnt_e, cnt_t, be, bt);
    bucket_csr<<<dim3(NBKT, 2), 256, 0, stream>>>(be, bt, cnt_e, cnt_t,
                                                  starts_e, ends_e, starts_t, ends_t,
                                                  se, st);
    aggregate2<<<NN / 4, 256, 0, stream>>>(entb, topb, starts_e, ends_e,
                                           starts_t, ends_t, se, st, X);
    mlp_fused<<<782, 256, 0, stream>>>(X, W1T, b1, W2T, b2, (float*)d_out);
}